// Round 1
// baseline (1466.788 us; speedup 1.0000x reference)
//
#include <hip/hip_runtime.h>
#include <math.h>

// ---------------------------------------------------------------------------
// CombinedHiddenGCVAE on MI355X — round 1: fp32 correctness-first baseline.
// Structure: aggregate-first GCN (A@X then GEMM), CSR-by-dst built on device,
// gather-reduce aggregation (no atomics in hot path), simple LDS-tiled fp32
// GEMM with fused bias(+tanh).
// ---------------------------------------------------------------------------

#define FEAT 128
#define COND 32
#define HID  128
#define LAT  64

// ---------------- prep kernels ----------------

__global__ void k_init(float* deg, int* cursor, int n) {
  int i = blockIdx.x * blockDim.x + threadIdx.x;
  if (i < n) { deg[i] = 1.0f; cursor[i] = 0; }
}

__global__ void k_count(const int* __restrict__ ei, float* deg, int E) {
  int e = blockIdx.x * blockDim.x + threadIdx.x;
  if (e < E) atomicAdd(&deg[ei[E + e]], 1.0f);  // dst = ei[E+e]
}

__global__ void k_dis(const float* __restrict__ deg, float* __restrict__ dis, int n) {
  int i = blockIdx.x * blockDim.x + threadIdx.x;
  if (i < n) dis[i] = rsqrtf(deg[i]);
}

// exclusive prefix scan of cnt[i] = (int)deg[i]-1, 1024 elems / block
__global__ void k_scan1(const float* __restrict__ deg, int* __restrict__ ptr,
                        int* __restrict__ blkSum, int n) {
  __shared__ int wtot[4];
  int tid = threadIdx.x, lane = tid & 63, wid = tid >> 6;
  int base = blockIdx.x * 1024 + tid * 4;
  int v[4];
#pragma unroll
  for (int j = 0; j < 4; j++) {
    int i = base + j;
    v[j] = (i < n) ? ((int)deg[i] - 1) : 0;
  }
  int tsum = v[0] + v[1] + v[2] + v[3];
  int x = tsum;
#pragma unroll
  for (int off = 1; off < 64; off <<= 1) {
    int y = __shfl_up(x, off);
    if (lane >= off) x += y;
  }
  if (lane == 63) wtot[wid] = x;
  __syncthreads();
  int wbase = 0;
  for (int w = 0; w < wid; w++) wbase += wtot[w];
  int run = wbase + (x - tsum);  // exclusive prefix of this thread in block
#pragma unroll
  for (int j = 0; j < 4; j++) {
    int i = base + j;
    if (i < n) ptr[i] = run;
    run += v[j];
  }
  if (tid == blockDim.x - 1) blkSum[blockIdx.x] = wbase + x;  // block total
}

// exclusive scan of up-to-256 block sums (single block, 256 threads)
__global__ void k_scan2(const int* __restrict__ blkSum, int* __restrict__ blkOff, int nb) {
  __shared__ int wtot[4];
  int tid = threadIdx.x, lane = tid & 63, wid = tid >> 6;
  int v = (tid < nb) ? blkSum[tid] : 0;
  int x = v;
#pragma unroll
  for (int off = 1; off < 64; off <<= 1) {
    int y = __shfl_up(x, off);
    if (lane >= off) x += y;
  }
  if (lane == 63) wtot[wid] = x;
  __syncthreads();
  int wbase = 0;
  for (int w = 0; w < wid; w++) wbase += wtot[w];
  if (tid < nb) blkOff[tid] = wbase + x - v;
}

__global__ void k_scan3(int* __restrict__ ptr, const int* __restrict__ blkOff, int n) {
  int i = blockIdx.x * blockDim.x + threadIdx.x;
  if (i < n) ptr[i] += blkOff[i >> 10];
}

__global__ void k_fill(const int* __restrict__ ei, const int* __restrict__ ptr,
                       int* __restrict__ cursor, int* __restrict__ csr, int E) {
  int e = blockIdx.x * blockDim.x + threadIdx.x;
  if (e < E) {
    int s = ei[e];
    int d = ei[E + e];
    int pos = ptr[d] + atomicAdd(&cursor[d], 1);
    csr[pos] = s;
  }
}

// ---------------- aggregation: Y[i] = dis_i*(dis_i*X[i] + sum_e dis[s_e]*X[s_e]) ----
// one wave per node; lanes cover columns.
template <int W>
__global__ __launch_bounds__(256) void k_agg(
    const float* __restrict__ X, float* __restrict__ Y,
    const float* __restrict__ deg, const float* __restrict__ dis,
    const int* __restrict__ ptr, const int* __restrict__ csr, int n) {
  int wv = blockIdx.x * 4 + (threadIdx.x >> 6);
  int lane = threadIdx.x & 63;
  if (wv >= n) return;
  const int i = wv;
  const float di = dis[i];
  constexpr int C = (W + 63) / 64;
  float acc[C];
#pragma unroll
  for (int c = 0; c < C; c++) {
    int col = lane + 64 * c;
    acc[c] = (col < W) ? di * X[(size_t)i * W + col] : 0.f;
  }
  int p0 = ptr[i];
  int cnt = (int)deg[i] - 1;
  int e = 0;
  for (; e + 1 < cnt; e += 2) {
    int s0 = csr[p0 + e];
    int s1 = csr[p0 + e + 1];
    float w0 = dis[s0];
    float w1 = dis[s1];
#pragma unroll
    for (int c = 0; c < C; c++) {
      int col = lane + 64 * c;
      if (col < W)
        acc[c] += w0 * X[(size_t)s0 * W + col] + w1 * X[(size_t)s1 * W + col];
    }
  }
  if (e < cnt) {
    int s0 = csr[p0 + e];
    float w0 = dis[s0];
#pragma unroll
    for (int c = 0; c < C; c++) {
      int col = lane + 64 * c;
      if (col < W) acc[c] += w0 * X[(size_t)s0 * W + col];
    }
  }
#pragma unroll
  for (int c = 0; c < C; c++) {
    int col = lane + 64 * c;
    if (col < W) Y[(size_t)i * W + col] = di * acc[c];
  }
}

// ---------------- GEMM: C = act(concat(A1,A2) @ Wt + bias) ----------------
// A1: [M,K1], A2: [M,K2] (may be null, K2=0), Wt: [K1+K2, NN] row-major.
// BM=64, BN=64, BK=32, 256 threads, 4x4 micro-tile.
template <bool TANH>
__global__ __launch_bounds__(256) void k_gemm(
    const float* __restrict__ A1, int K1,
    const float* __restrict__ A2, int K2,
    const float* __restrict__ Wt, const float* __restrict__ bias,
    float* __restrict__ C, int M, int NN) {
  __shared__ float As[64][33];
  __shared__ __align__(16) float Bs[32][64];
  const int tid = threadIdx.x;
  const int m0 = blockIdx.x * 64;
  const int n0 = blockIdx.y * 64;
  const int K = K1 + K2;
  const int tx = tid & 15, ty = tid >> 4;
  float acc[4][4] = {};
  for (int kt = 0; kt < K; kt += 32) {
    {  // A tile: 64 rows x 32 k
      int kl = tid & 31, rbase = tid >> 5;
#pragma unroll
      for (int p = 0; p < 8; p++) {
        int r = rbase + p * 8;
        int row = m0 + r;
        int kg = kt + kl;
        float a = 0.f;
        if (row < M) {
          a = (kg < K1) ? A1[(size_t)row * K1 + kg]
                        : A2[(size_t)row * K2 + (kg - K1)];
        }
        As[r][kl] = a;
      }
    }
    {  // B tile: 32 k x 64 n
      int cl = tid & 63, kbase = tid >> 6;
#pragma unroll
      for (int p = 0; p < 8; p++) {
        int k = kbase + p * 4;
        Bs[k][cl] = Wt[(size_t)(kt + k) * NN + (n0 + cl)];
      }
    }
    __syncthreads();
#pragma unroll
    for (int k = 0; k < 32; k++) {
      float a[4];
#pragma unroll
      for (int i = 0; i < 4; i++) a[i] = As[ty * 4 + i][k];
      float4 bv = *(const float4*)&Bs[k][tx * 4];
      float b[4] = {bv.x, bv.y, bv.z, bv.w};
#pragma unroll
      for (int i = 0; i < 4; i++)
#pragma unroll
        for (int j = 0; j < 4; j++) acc[i][j] += a[i] * b[j];
    }
    __syncthreads();
  }
  float4 bb = *(const float4*)&bias[n0 + tx * 4];
  float b4[4] = {bb.x, bb.y, bb.z, bb.w};
#pragma unroll
  for (int i = 0; i < 4; i++) {
    int row = m0 + ty * 4 + i;
    if (row < M) {
      float4 o;
      float* op = (float*)&o;
#pragma unroll
      for (int j = 0; j < 4; j++) {
        float v = acc[i][j] + b4[j];
        if (TANH) v = tanhf(v);
        op[j] = v;
      }
      *(float4*)&C[(size_t)row * NN + n0 + tx * 4] = o;
    }
  }
}

// ---------------- reparameterization ----------------
__global__ void k_z(const float* __restrict__ noise, const float* __restrict__ mean,
                    const float* __restrict__ logvar, float* __restrict__ z, int n) {
  int i = blockIdx.x * blockDim.x + threadIdx.x;
  if (i < n) z[i] = noise[i] * expf(0.5f * logvar[i]) + mean[i];
}

// ---------------------------------------------------------------------------

static inline size_t align_up(size_t x, size_t a) { return (x + a - 1) & ~(a - 1); }

extern "C" void kernel_launch(void* const* d_in, const int* in_sizes, int n_in,
                              void* d_out, int out_size, void* d_ws, size_t ws_size,
                              hipStream_t stream) {
  const float* feature   = (const float*)d_in[0];
  const float* condition = (const float*)d_in[1];
  const float* noise     = (const float*)d_in[2];
  const int*   ei        = (const int*)d_in[3];
  const float* Wenc1 = (const float*)d_in[4];  const float* benc1 = (const float*)d_in[5];
  const float* Wenc2 = (const float*)d_in[6];  const float* benc2 = (const float*)d_in[7];
  const float* Wm    = (const float*)d_in[8];  const float* bm    = (const float*)d_in[9];
  const float* Wlv   = (const float*)d_in[10]; const float* blv   = (const float*)d_in[11];
  const float* Wd1   = (const float*)d_in[12]; const float* bd1   = (const float*)d_in[13];
  const float* Wd2   = (const float*)d_in[14]; const float* bd2   = (const float*)d_in[15];
  const float* Wout  = (const float*)d_in[16]; const float* bout  = (const float*)d_in[17];

  const int N = in_sizes[0] / FEAT;      // 100000
  const int E = in_sizes[3] / 2;         // 1600000

  // ---- d_out segments (z, mean, logvar, out) ----
  float* out = (float*)d_out;
  float* zseg    = out;                       // [N,64]
  float* meanseg = out + (size_t)N * LAT;     // [N,64]
  float* lvseg   = out + (size_t)2 * N * LAT; // [N,64]
  float* outseg  = out + (size_t)3 * N * LAT; // [N,128] — doubles as scratch B1

  // ---- workspace layout ----
  char* w = (char*)d_ws;
  size_t off = 0;
  float* deg    = (float*)(w + off); off = align_up(off + (size_t)N * 4, 256);
  float* dis    = (float*)(w + off); off = align_up(off + (size_t)N * 4, 256);
  int*   ptr    = (int*)(w + off);   off = align_up(off + (size_t)N * 4, 256);
  int*   cursor = (int*)(w + off);   off = align_up(off + (size_t)N * 4, 256);
  int*   blkSum = (int*)(w + off);   off = align_up(off + 4096, 256);
  int*   blkOff = (int*)(w + off);   off = align_up(off + 4096, 256);
  int*   csr    = (int*)(w + off);   off = align_up(off + (size_t)E * 4, 256);
  float* B2     = (float*)(w + off); off = align_up(off + (size_t)N * HID * 4, 256);
  float* S      = (float*)(w + off); off = align_up(off + (size_t)N * COND * 4, 256);
  float* B1     = outseg;  // [N,128] scratch inside d_out's final segment

  const int TB = 256;
  dim3 blk(TB);
  dim3 gN((N + TB - 1) / TB);
  dim3 gE((E + TB - 1) / TB);
  const int nScanBlk = (N + 1023) / 1024;  // 98 — must be <= 256 for k_scan2
  dim3 gAgg((N + 3) / 4);
  dim3 gGemmM((N + 63) / 64);

  // ---- graph prep: degrees, norms, CSR ----
  k_init<<<gN, blk, 0, stream>>>(deg, cursor, N);
  k_count<<<gE, blk, 0, stream>>>(ei, deg, E);
  k_dis<<<gN, blk, 0, stream>>>(deg, dis, N);
  k_scan1<<<dim3(nScanBlk), blk, 0, stream>>>(deg, ptr, blkSum, N);
  k_scan2<<<dim3(1), blk, 0, stream>>>(blkSum, blkOff, nScanBlk);
  k_scan3<<<gN, blk, 0, stream>>>(ptr, blkOff, N);
  k_fill<<<gE, blk, 0, stream>>>(ei, ptr, cursor, csr, E);

  // ---- encoder ----
  // aggF = agg(feature) -> B1 ; aggC = agg(condition) -> S
  k_agg<FEAT><<<gAgg, blk, 0, stream>>>(feature, B1, deg, dis, ptr, csr, N);
  k_agg<COND><<<gAgg, blk, 0, stream>>>(condition, S, deg, dis, ptr, csr, N);
  // h1 = tanh([aggF|aggC] @ Wenc1 + b) -> B2
  k_gemm<true><<<dim3(gGemmM.x, HID / 64), blk, 0, stream>>>(
      B1, FEAT, S, COND, Wenc1, benc1, B2, N, HID);
  // aggH1 -> B1
  k_agg<HID><<<gAgg, blk, 0, stream>>>(B2, B1, deg, dis, ptr, csr, N);
  // h2 = tanh(aggH1 @ Wenc2 + b) -> B2
  k_gemm<true><<<dim3(gGemmM.x, HID / 64), blk, 0, stream>>>(
      B1, HID, nullptr, 0, Wenc2, benc2, B2, N, HID);
  // aggH2 -> B1 (shared by mean & logvar)
  k_agg<HID><<<gAgg, blk, 0, stream>>>(B2, B1, deg, dis, ptr, csr, N);
  // mean, logvar -> d_out segments
  k_gemm<false><<<dim3(gGemmM.x, LAT / 64), blk, 0, stream>>>(
      B1, HID, nullptr, 0, Wm, bm, meanseg, N, LAT);
  k_gemm<false><<<dim3(gGemmM.x, LAT / 64), blk, 0, stream>>>(
      B1, HID, nullptr, 0, Wlv, blv, lvseg, N, LAT);
  // z = noise * exp(0.5*logvar) + mean -> d_out
  k_z<<<dim3(((size_t)N * LAT + TB - 1) / TB), blk, 0, stream>>>(
      noise, meanseg, lvseg, zseg, N * LAT);

  // ---- decoder ----
  // aggZ -> B2 (first N*64)
  k_agg<LAT><<<gAgg, blk, 0, stream>>>(zseg, B2, deg, dis, ptr, csr, N);
  // g1 = tanh([aggZ|aggC] @ Wd1 + b) -> B1
  k_gemm<true><<<dim3(gGemmM.x, HID / 64), blk, 0, stream>>>(
      B2, LAT, S, COND, Wd1, bd1, B1, N, HID);
  // aggG1 -> B2
  k_agg<HID><<<gAgg, blk, 0, stream>>>(B1, B2, deg, dis, ptr, csr, N);
  // g2 = tanh(aggG1 @ Wd2 + b) -> B1
  k_gemm<true><<<dim3(gGemmM.x, HID / 64), blk, 0, stream>>>(
      B2, HID, nullptr, 0, Wd2, bd2, B1, N, HID);
  // aggG2 -> B2
  k_agg<HID><<<gAgg, blk, 0, stream>>>(B1, B2, deg, dis, ptr, csr, N);
  // out = aggG2 @ Wout + b -> outseg (overwrites dead g2/B1)
  k_gemm<false><<<dim3(gGemmM.x, FEAT / 64), blk, 0, stream>>>(
      B2, HID, nullptr, 0, Wout, bout, outseg, N, FEAT);
}

// Round 2
// 1055.551 us; speedup vs baseline: 1.3896x; 1.3896x over previous
//
#include <hip/hip_runtime.h>
#include <hip/hip_fp16.h>
#include <math.h>

// ---------------------------------------------------------------------------
// CombinedHiddenGCVAE — round 2: f16 intermediate tables (halved gather bytes),
// dis-prescaled rows (no per-edge weight gather), MFMA f16 GEMMs with fused
// bias/tanh/reparam epilogues, mean+logvar fused into one GEMM.
// ---------------------------------------------------------------------------

#define FEAT 128
#define COND 32
#define HID  128
#define LAT  64

typedef _Float16 f16x8 __attribute__((ext_vector_type(8)));
typedef float f32x4 __attribute__((ext_vector_type(4)));

__device__ __forceinline__ float2 up2(uint u) {
  __half2 h = __builtin_bit_cast(__half2, u);
  return __half22float2(h);
}
__device__ __forceinline__ uint pk2(float x, float y) {
  __half2 h = __floats2half2_rn(x, y);
  return __builtin_bit_cast(uint, h);
}

// ---------------- prep kernels (unchanged from round 1) ----------------

__global__ void k_init(float* deg, int* cursor, int n) {
  int i = blockIdx.x * blockDim.x + threadIdx.x;
  if (i < n) { deg[i] = 1.0f; cursor[i] = 0; }
}

__global__ void k_count(const int* __restrict__ ei, float* deg, int E) {
  int e = blockIdx.x * blockDim.x + threadIdx.x;
  if (e < E) atomicAdd(&deg[ei[E + e]], 1.0f);
}

__global__ void k_dis(const float* __restrict__ deg, float* __restrict__ dis, int n) {
  int i = blockIdx.x * blockDim.x + threadIdx.x;
  if (i < n) dis[i] = rsqrtf(deg[i]);
}

__global__ void k_scan1(const float* __restrict__ deg, int* __restrict__ ptr,
                        int* __restrict__ blkSum, int n) {
  __shared__ int wtot[4];
  int tid = threadIdx.x, lane = tid & 63, wid = tid >> 6;
  int base = blockIdx.x * 1024 + tid * 4;
  int v[4];
#pragma unroll
  for (int j = 0; j < 4; j++) {
    int i = base + j;
    v[j] = (i < n) ? ((int)deg[i] - 1) : 0;
  }
  int tsum = v[0] + v[1] + v[2] + v[3];
  int x = tsum;
#pragma unroll
  for (int off = 1; off < 64; off <<= 1) {
    int y = __shfl_up(x, off);
    if (lane >= off) x += y;
  }
  if (lane == 63) wtot[wid] = x;
  __syncthreads();
  int wbase = 0;
  for (int w = 0; w < wid; w++) wbase += wtot[w];
  int run = wbase + (x - tsum);
#pragma unroll
  for (int j = 0; j < 4; j++) {
    int i = base + j;
    if (i < n) ptr[i] = run;
    run += v[j];
  }
  if (tid == blockDim.x - 1) blkSum[blockIdx.x] = wbase + x;
}

__global__ void k_scan2(const int* __restrict__ blkSum, int* __restrict__ blkOff, int nb) {
  __shared__ int wtot[4];
  int tid = threadIdx.x, lane = tid & 63, wid = tid >> 6;
  int v = (tid < nb) ? blkSum[tid] : 0;
  int x = v;
#pragma unroll
  for (int off = 1; off < 64; off <<= 1) {
    int y = __shfl_up(x, off);
    if (lane >= off) x += y;
  }
  if (lane == 63) wtot[wid] = x;
  __syncthreads();
  int wbase = 0;
  for (int w = 0; w < wid; w++) wbase += wtot[w];
  if (tid < nb) blkOff[tid] = wbase + x - v;
}

__global__ void k_scan3(int* __restrict__ ptr, const int* __restrict__ blkOff, int n) {
  int i = blockIdx.x * blockDim.x + threadIdx.x;
  if (i < n) ptr[i] += blkOff[i >> 10];
}

__global__ void k_fill(const int* __restrict__ ei, const int* __restrict__ ptr,
                       int* __restrict__ cursor, int* __restrict__ csr, int E) {
  int e = blockIdx.x * blockDim.x + threadIdx.x;
  if (e < E) {
    int s = ei[e];
    int d = ei[E + e];
    int pos = ptr[d] + atomicAdd(&cursor[d], 1);
    csr[pos] = s;
  }
}

// ---------------- fp32 -> f16 cast with dis prescale ----------------
// dst[row][c] = (half)(dis[row] * src[row][c]); LW = log2(row width)
template <int LW>
__global__ void k_cast(const float* __restrict__ src, uint* __restrict__ dst,
                       const float* __restrict__ dis, int n4) {
  int t = blockIdx.x * blockDim.x + threadIdx.x;
  if (t >= n4) return;
  size_t i4 = (size_t)t * 4;
  int row = (int)(i4 >> LW);
  float d = dis[row];
  float4 v = *(const float4*)&src[i4];
  uint2 o;
  o.x = pk2(d * v.x, d * v.y);
  o.y = pk2(d * v.z, d * v.w);
  *(uint2*)&dst[t * 2] = o;
}

// ---------------- weight pack: fp32 [K,N] -> f16 fragment layout ----------
// dst[((k>>3)*NnTot + colOff + n)*8 + (k&7)] = (half)src[k*Ncols + n]
struct PW { const float* src; unsigned short* dst; int K, Ncols, colOff, NnTot; };
struct PWArr { PW d[7]; };

__global__ void k_packw(PWArr a) {
  PW d = a.d[blockIdx.y];
  int t = blockIdx.x * blockDim.x + threadIdx.x;
  if (t >= d.K * d.Ncols) return;
  int k = t / d.Ncols;
  int n = t - k * d.Ncols;
  float v = d.src[t];
  d.dst[((size_t)(k >> 3) * d.NnTot + d.colOff + n) * 8 + (k & 7)] =
      __builtin_bit_cast(unsigned short, (_Float16)v);
}

// ---------------- aggregation over pre-scaled f16 rows --------------------
// Y[i] = (half) dis[i] * ( X[i] + sum_{s in nbr(i)} X[s] )   (X pre-scaled)
template <int W>
__global__ __launch_bounds__(256) void k_aggh(
    const uint* __restrict__ X, uint* __restrict__ Y,
    const float* __restrict__ deg, const float* __restrict__ dis,
    const int* __restrict__ ptr, const int* __restrict__ csr, int n) {
  constexpr int CP = W / 2;      // u32 (=2 f16) per row
  constexpr int NB = 64 / CP;    // neighbors processed per iteration
  int wv = blockIdx.x * 4 + (threadIdx.x >> 6);
  if (wv >= n) return;
  int l = threadIdx.x & 63;
  int c = l & (CP - 1);
  int sub = l / CP;
  const int i = wv;
  float2 acc;
  {
    float2 f = up2(X[(size_t)i * CP + c]);
    acc.x = (sub == 0) ? f.x : 0.f;
    acc.y = (sub == 0) ? f.y : 0.f;
  }
  int p0 = ptr[i];
  int cnt = (int)deg[i] - 1;
  if (NB == 1) {
    int e = 0;
    for (; e + 1 < cnt; e += 2) {
      int s0 = csr[p0 + e];
      int s1 = csr[p0 + e + 1];
      float2 f0 = up2(X[(size_t)s0 * CP + c]);
      float2 f1 = up2(X[(size_t)s1 * CP + c]);
      acc.x += f0.x + f1.x;
      acc.y += f0.y + f1.y;
    }
    if (e < cnt) {
      int s0 = csr[p0 + e];
      float2 f0 = up2(X[(size_t)s0 * CP + c]);
      acc.x += f0.x;
      acc.y += f0.y;
    }
  } else {
    for (int e = 0; e < cnt; e += NB) {
      int idx = e + sub;
      if (idx < cnt) {
        int s = csr[p0 + idx];
        float2 f = up2(X[(size_t)s * CP + c]);
        acc.x += f.x;
        acc.y += f.y;
      }
    }
    acc.x += __shfl_xor(acc.x, 32);
    acc.y += __shfl_xor(acc.y, 32);
    if (NB == 4) {
      acc.x += __shfl_xor(acc.x, 16);
      acc.y += __shfl_xor(acc.y, 16);
    }
  }
  if (sub == 0) {
    float di = dis[i];
    Y[(size_t)i * CP + c] = pk2(di * acc.x, di * acc.y);
  }
}

// ---------------- MFMA f16 GEMM, NN=128, BM=128 (4 waves x 32 rows) -------
// A = concat(A1[M,K1], A2[M,K2]) f16 (K1,K2 multiples of 32 at tile bounds).
// Wp: packed f16 weights (k-octet fragment layout). MODE:
//   0: Of16[row][c] = dis[row]*tanh(v)          (hidden layers)
//   1: mean/lv/z fused (O1=mean, O2=lv, O3=z fp32; Of16 = dis*z, width 64)
//   2: O1[row][c] = v  (fp32 final out)
template <int MODE>
__global__ __launch_bounds__(256) void k_gemm16(
    const _Float16* __restrict__ A1, int K1,
    const _Float16* __restrict__ A2, int K2,
    const unsigned short* __restrict__ Wp,
    const float* __restrict__ b1, const float* __restrict__ b2,
    float* __restrict__ O1, float* __restrict__ O2, float* __restrict__ O3,
    _Float16* __restrict__ Of16,
    const float* __restrict__ noise, const float* __restrict__ dis, int M) {
  __shared__ unsigned short wl[20 * 1024];  // up to K=160: (K/8)*128*8 f16
  const int tid = threadIdx.x;
  const int l = tid & 63, wid = tid >> 6;
  const int row0 = blockIdx.x * 128;
  const int K = K1 + K2;
  const int totalU16 = (K >> 3) << 10;
  for (int o = tid * 8; o < totalU16; o += 256 * 8) {
    *(uint4*)&wl[o] = *(const uint4*)&Wp[o];
  }
  __syncthreads();

  const int ar = l & 15, kg = l >> 4;
  f32x4 acc[2][8] = {};
  for (int k0 = 0; k0 < K; k0 += 32) {
    const _Float16* Ab;
    int kl, Kb;
    if (k0 < K1) { Ab = A1; kl = k0; Kb = K1; }
    else         { Ab = A2; kl = k0 - K1; Kb = K2; }
    f16x8 a[2];
#pragma unroll
    for (int mt = 0; mt < 2; mt++) {
      int row = row0 + wid * 32 + mt * 16 + ar;
      if (row < M) {
        a[mt] = *(const f16x8*)&Ab[(size_t)row * Kb + kl + kg * 8];
      } else {
#pragma unroll
        for (int j = 0; j < 8; j++) a[mt][j] = (_Float16)0;
      }
    }
    int lb = ((k0 >> 3) + kg) * 1024 + ar * 8;
#pragma unroll
    for (int nt = 0; nt < 8; nt++) {
      f16x8 b = *(const f16x8*)&wl[lb + nt * 128];
#pragma unroll
      for (int mt = 0; mt < 2; mt++)
        acc[mt][nt] = __builtin_amdgcn_mfma_f32_16x16x32_f16(a[mt], b, acc[mt][nt], 0, 0, 0);
    }
  }

  // epilogue: D row = (l>>4)*4 + r, col = nt*16 + (l&15)
#pragma unroll
  for (int mt = 0; mt < 2; mt++) {
    int rbase = row0 + wid * 32 + mt * 16 + (l >> 4) * 4;
#pragma unroll
    for (int r = 0; r < 4; r++) {
      int rw = rbase + r;
      if (rw >= M) continue;
      if (MODE == 1) {
        float dr = dis[rw];
#pragma unroll
        for (int nt = 0; nt < 4; nt++) {
          int c = nt * 16 + (l & 15);
          float mv = acc[mt][nt][r] + b1[c];
          float lv = acc[mt][nt + 4][r] + b2[c];
          O1[(size_t)rw * 64 + c] = mv;
          O2[(size_t)rw * 64 + c] = lv;
          float z = noise[(size_t)rw * 64 + c] * expf(0.5f * lv) + mv;
          O3[(size_t)rw * 64 + c] = z;
          Of16[(size_t)rw * 64 + c] = (_Float16)(dr * z);
        }
      } else if (MODE == 0) {
        float dr = dis[rw];
#pragma unroll
        for (int nt = 0; nt < 8; nt++) {
          int c = nt * 16 + (l & 15);
          float v = tanhf(acc[mt][nt][r] + b1[c]);
          Of16[(size_t)rw * 128 + c] = (_Float16)(dr * v);
        }
      } else {
#pragma unroll
        for (int nt = 0; nt < 8; nt++) {
          int c = nt * 16 + (l & 15);
          O1[(size_t)rw * 128 + c] = acc[mt][nt][r] + b1[c];
        }
      }
    }
  }
}

// ---------------------------------------------------------------------------

static inline size_t align_up(size_t x, size_t a) { return (x + a - 1) & ~(a - 1); }

extern "C" void kernel_launch(void* const* d_in, const int* in_sizes, int n_in,
                              void* d_out, int out_size, void* d_ws, size_t ws_size,
                              hipStream_t stream) {
  const float* feature   = (const float*)d_in[0];
  const float* condition = (const float*)d_in[1];
  const float* noise     = (const float*)d_in[2];
  const int*   ei        = (const int*)d_in[3];
  const float* Wenc1 = (const float*)d_in[4];  const float* benc1 = (const float*)d_in[5];
  const float* Wenc2 = (const float*)d_in[6];  const float* benc2 = (const float*)d_in[7];
  const float* Wm    = (const float*)d_in[8];  const float* bm    = (const float*)d_in[9];
  const float* Wlv   = (const float*)d_in[10]; const float* blv   = (const float*)d_in[11];
  const float* Wd1   = (const float*)d_in[12]; const float* bd1   = (const float*)d_in[13];
  const float* Wd2   = (const float*)d_in[14]; const float* bd2   = (const float*)d_in[15];
  const float* Wout  = (const float*)d_in[16]; const float* bout  = (const float*)d_in[17];

  const int N = in_sizes[0] / FEAT;
  const int E = in_sizes[3] / 2;

  // ---- d_out segments ----
  float* out = (float*)d_out;
  float* zseg    = out;
  float* meanseg = out + (size_t)N * LAT;
  float* lvseg   = out + (size_t)2 * N * LAT;
  float* outseg  = out + (size_t)3 * N * LAT;  // [N,128] fp32; scratch until final GEMM

  // f16 staging buffers aliased into outseg (dead until final GEMM):
  char* ob = (char*)outseg;
  uint* featF = (uint*)ob;                                 // [N,128] f16 = N*64 u32
  uint* condF = (uint*)(ob + (size_t)N * 128 * 2);         // [N,32] f16
  _Float16* zf16 = (_Float16*)(ob + (size_t)N * 160 * 2);  // [N,64] f16
  uint* zf16u = (uint*)zf16;

  // ---- workspace ----
  char* w = (char*)d_ws;
  size_t off = 0;
  float* deg    = (float*)(w + off); off = align_up(off + (size_t)N * 4, 256);
  float* dis    = (float*)(w + off); off = align_up(off + (size_t)N * 4, 256);
  int*   ptr    = (int*)(w + off);   off = align_up(off + (size_t)N * 4, 256);
  int*   cursor = (int*)(w + off);   off = align_up(off + (size_t)N * 4, 256);
  int*   blkSum = (int*)(w + off);   off = align_up(off + 4096, 256);
  int*   blkOff = (int*)(w + off);   off = align_up(off + 4096, 256);
  int*   csr    = (int*)(w + off);   off = align_up(off + (size_t)(E + 8) * 4, 256);
  unsigned short* WpE1 = (unsigned short*)(w + off); off = align_up(off + 160 * 128 * 2, 256);
  unsigned short* WpE2 = (unsigned short*)(w + off); off = align_up(off + 128 * 128 * 2, 256);
  unsigned short* WpML = (unsigned short*)(w + off); off = align_up(off + 128 * 128 * 2, 256);
  unsigned short* WpD1 = (unsigned short*)(w + off); off = align_up(off + 96 * 128 * 2, 256);
  unsigned short* WpD2 = (unsigned short*)(w + off); off = align_up(off + 128 * 128 * 2, 256);
  unsigned short* WpO  = (unsigned short*)(w + off); off = align_up(off + 128 * 128 * 2, 256);
  uint* S  = (uint*)(w + off); off = align_up(off + (size_t)N * 32 * 2, 256);
  uint* T1 = (uint*)(w + off); off = align_up(off + (size_t)N * 128 * 2, 256);
  uint* T2 = (uint*)(w + off); off = align_up(off + (size_t)N * 128 * 2, 256);

  const int TB = 256;
  dim3 blk(TB);
  dim3 gN((N + TB - 1) / TB);
  dim3 gE((E + TB - 1) / TB);
  const int nScanBlk = (N + 1023) / 1024;
  dim3 gAgg((N + 3) / 4);
  dim3 gG((N + 127) / 128);

  // ---- prep ----
  k_init<<<gN, blk, 0, stream>>>(deg, cursor, N);
  k_count<<<gE, blk, 0, stream>>>(ei, deg, E);
  k_dis<<<gN, blk, 0, stream>>>(deg, dis, N);
  k_scan1<<<dim3(nScanBlk), blk, 0, stream>>>(deg, ptr, blkSum, N);
  k_scan2<<<dim3(1), blk, 0, stream>>>(blkSum, blkOff, nScanBlk);
  k_scan3<<<gN, blk, 0, stream>>>(ptr, blkOff, N);
  k_fill<<<gE, blk, 0, stream>>>(ei, ptr, cursor, csr, E);

  // ---- casts + weight packing ----
  k_cast<7><<<dim3(((size_t)N * 128 / 4 + TB - 1) / TB), blk, 0, stream>>>(
      feature, featF, dis, N * 128 / 4);
  k_cast<5><<<dim3(((size_t)N * 32 / 4 + TB - 1) / TB), blk, 0, stream>>>(
      condition, condF, dis, N * 32 / 4);
  {
    PWArr pa;
    pa.d[0] = {Wenc1, WpE1, 160, 128, 0, 128};
    pa.d[1] = {Wenc2, WpE2, 128, 128, 0, 128};
    pa.d[2] = {Wm,    WpML, 128, 64,  0, 128};
    pa.d[3] = {Wlv,   WpML, 128, 64, 64, 128};
    pa.d[4] = {Wd1,   WpD1,  96, 128, 0, 128};
    pa.d[5] = {Wd2,   WpD2, 128, 128, 0, 128};
    pa.d[6] = {Wout,  WpO,  128, 128, 0, 128};
    k_packw<<<dim3(80, 7), blk, 0, stream>>>(pa);
  }

  // ---- encoder ----
  k_aggh<FEAT><<<gAgg, blk, 0, stream>>>(featF, T1, deg, dis, ptr, csr, N);
  k_aggh<COND><<<gAgg, blk, 0, stream>>>(condF, S, deg, dis, ptr, csr, N);
  k_gemm16<0><<<gG, blk, 0, stream>>>(
      (const _Float16*)T1, FEAT, (const _Float16*)S, COND, WpE1, benc1, nullptr,
      nullptr, nullptr, nullptr, (_Float16*)T2, nullptr, dis, N);
  k_aggh<HID><<<gAgg, blk, 0, stream>>>(T2, T1, deg, dis, ptr, csr, N);
  k_gemm16<0><<<gG, blk, 0, stream>>>(
      (const _Float16*)T1, HID, nullptr, 0, WpE2, benc2, nullptr,
      nullptr, nullptr, nullptr, (_Float16*)T2, nullptr, dis, N);
  k_aggh<HID><<<gAgg, blk, 0, stream>>>(T2, T1, deg, dis, ptr, csr, N);
  // mean | logvar fused GEMM + reparameterization epilogue
  k_gemm16<1><<<gG, blk, 0, stream>>>(
      (const _Float16*)T1, HID, nullptr, 0, WpML, bm, blv,
      meanseg, lvseg, zseg, zf16, noise, dis, N);

  // ---- decoder ----
  k_aggh<LAT><<<gAgg, blk, 0, stream>>>(zf16u, T1, deg, dis, ptr, csr, N);
  k_gemm16<0><<<gG, blk, 0, stream>>>(
      (const _Float16*)T1, LAT, (const _Float16*)S, COND, WpD1, bd1, nullptr,
      nullptr, nullptr, nullptr, (_Float16*)T2, nullptr, dis, N);
  k_aggh<HID><<<gAgg, blk, 0, stream>>>(T2, T1, deg, dis, ptr, csr, N);
  k_gemm16<0><<<gG, blk, 0, stream>>>(
      (const _Float16*)T1, HID, nullptr, 0, WpD2, bd2, nullptr,
      nullptr, nullptr, nullptr, (_Float16*)T2, nullptr, dis, N);
  k_aggh<HID><<<gAgg, blk, 0, stream>>>(T2, T1, deg, dis, ptr, csr, N);
  k_gemm16<2><<<gG, blk, 0, stream>>>(
      (const _Float16*)T1, HID, nullptr, 0, WpO, bout, nullptr,
      outseg, nullptr, nullptr, nullptr, nullptr, dis, N);
}

// Round 3
// 843.743 us; speedup vs baseline: 1.7384x; 1.2510x over previous
//
#include <hip/hip_runtime.h>
#include <hip/hip_fp16.h>
#include <math.h>

// ---------------------------------------------------------------------------
// CombinedHiddenGCVAE — round 3:
//  - XCD-range-partitioned CSR build (8 block-groups, each owns a dst range):
//    kills the 16x write amplification of scattered 4B stores/atomics.
//  - Aggregation with 16B/lane gathers (f16x8), 4-16 rows in flight, f32
//    accumulate + shfl_xor subgroup reduce.
//  - MFMA f16 GEMMs, LDS sized by compile-time K.
// ---------------------------------------------------------------------------

#define FEAT 128
#define COND 32
#define HID  128
#define LAT  64

typedef _Float16 f16x8 __attribute__((ext_vector_type(8)));
typedef float f32x4 __attribute__((ext_vector_type(4)));

__device__ __forceinline__ uint pk2(float x, float y) {
  __half2 h = __floats2half2_rn(x, y);
  return __builtin_bit_cast(uint, h);
}

// ---------------- prep kernels ----------------

__global__ void k_init(float* deg, int n) {
  int i = blockIdx.x * blockDim.x + threadIdx.x;
  if (i < n) deg[i] = 1.0f;
}

// 8-group range-partitioned degree count: group g handles dst in [lo,hi)
__global__ void k_count8(const int* __restrict__ dstArr, float* deg, int E, int n) {
  int g = blockIdx.x & 7;
  int lo = (g * n) / 8, hi = ((g + 1) * n) / 8;
  int nb = gridDim.x >> 3;
  int bi = blockIdx.x >> 3;
  int stride = nb * blockDim.x;
  for (int e = bi * blockDim.x + threadIdx.x; e < E; e += stride) {
    int d = dstArr[e];
    if (d >= lo && d < hi) atomicAdd(&deg[d], 1.0f);
  }
}

// scan step 1 (+ dis computation folded in)
__global__ void k_scan1(const float* __restrict__ deg, float* __restrict__ dis,
                        int* __restrict__ ptr, int* __restrict__ blkSum, int n) {
  __shared__ int wtot[4];
  int tid = threadIdx.x, lane = tid & 63, wid = tid >> 6;
  int base = blockIdx.x * 1024 + tid * 4;
  int v[4];
#pragma unroll
  for (int j = 0; j < 4; j++) {
    int i = base + j;
    float dg = (i < n) ? deg[i] : 1.0f;
    v[j] = (int)dg - 1;
    if (i < n) dis[i] = rsqrtf(dg);
  }
  int tsum = v[0] + v[1] + v[2] + v[3];
  int x = tsum;
#pragma unroll
  for (int off = 1; off < 64; off <<= 1) {
    int y = __shfl_up(x, off);
    if (lane >= off) x += y;
  }
  if (lane == 63) wtot[wid] = x;
  __syncthreads();
  int wbase = 0;
  for (int w = 0; w < wid; w++) wbase += wtot[w];
  int run = wbase + (x - tsum);
#pragma unroll
  for (int j = 0; j < 4; j++) {
    int i = base + j;
    if (i < n) ptr[i] = run;
    run += v[j];
  }
  if (tid == blockDim.x - 1) blkSum[blockIdx.x] = wbase + x;
}

__global__ void k_scan2(const int* __restrict__ blkSum, int* __restrict__ blkOff, int nb) {
  __shared__ int wtot[4];
  int tid = threadIdx.x, lane = tid & 63, wid = tid >> 6;
  int v = (tid < nb) ? blkSum[tid] : 0;
  int x = v;
#pragma unroll
  for (int off = 1; off < 64; off <<= 1) {
    int y = __shfl_up(x, off);
    if (lane >= off) x += y;
  }
  if (lane == 63) wtot[wid] = x;
  __syncthreads();
  int wbase = 0;
  for (int w = 0; w < wid; w++) wbase += wtot[w];
  if (tid < nb) blkOff[tid] = wbase + x - v;
}

// scan step 3 (+ cursor zero-init folded in)
__global__ void k_scan3(int* __restrict__ ptr, const int* __restrict__ blkOff,
                        int* __restrict__ cursor, int n) {
  int i = blockIdx.x * blockDim.x + threadIdx.x;
  if (i < n) {
    ptr[i] += blkOff[i >> 10];
    cursor[i] = 0;
  }
}

// 8-group range-partitioned CSR fill
__global__ void k_fill8(const int* __restrict__ ei, const int* __restrict__ ptr,
                        int* __restrict__ cursor, int* __restrict__ csr, int E, int n) {
  int g = blockIdx.x & 7;
  int lo = (g * n) / 8, hi = ((g + 1) * n) / 8;
  int nb = gridDim.x >> 3;
  int bi = blockIdx.x >> 3;
  int stride = nb * blockDim.x;
  for (int e = bi * blockDim.x + threadIdx.x; e < E; e += stride) {
    int d = ei[E + e];
    if (d >= lo && d < hi) {
      int s = ei[e];
      int pos = ptr[d] + atomicAdd(&cursor[d], 1);
      csr[pos] = s;
    }
  }
}

// ---------------- fp32 -> f16 cast with dis prescale ----------------
template <int LW>
__global__ void k_cast(const float* __restrict__ src, uint* __restrict__ dst,
                       const float* __restrict__ dis, int n4) {
  int t = blockIdx.x * blockDim.x + threadIdx.x;
  if (t >= n4) return;
  size_t i4 = (size_t)t * 4;
  int row = (int)(i4 >> LW);
  float d = dis[row];
  float4 v = *(const float4*)&src[i4];
  uint2 o;
  o.x = pk2(d * v.x, d * v.y);
  o.y = pk2(d * v.z, d * v.w);
  *(uint2*)&dst[t * 2] = o;
}

// ---------------- weight pack: fp32 [K,N] -> f16 fragment layout ----------
struct PW { const float* src; unsigned short* dst; int K, Ncols, colOff, NnTot; };
struct PWArr { PW d[7]; };

__global__ void k_packw(PWArr a) {
  PW d = a.d[blockIdx.y];
  int t = blockIdx.x * blockDim.x + threadIdx.x;
  if (t >= d.K * d.Ncols) return;
  int k = t / d.Ncols;
  int n = t - k * d.Ncols;
  float v = d.src[t];
  d.dst[((size_t)(k >> 3) * d.NnTot + d.colOff + n) * 8 + (k & 7)] =
      __builtin_bit_cast(unsigned short, (_Float16)v);
}

// ---------------- aggregation over pre-scaled f16 rows --------------------
// Y[i] = (f16) dis[i] * ( X[i] + sum_{s in nbr(i)} X[s] )   (X pre-scaled)
// CPL = W/8 lanes per row, 16B per lane; NB = 64/CPL rows in flight.
template <int W>
__global__ __launch_bounds__(256) void k_aggh(
    const _Float16* __restrict__ X, _Float16* __restrict__ Y,
    const float* __restrict__ deg, const float* __restrict__ dis,
    const int* __restrict__ ptr, const int* __restrict__ csr, int n) {
  constexpr int CPL = W / 8;
  constexpr int NB = 64 / CPL;
  int wv = blockIdx.x * 4 + (threadIdx.x >> 6);
  if (wv >= n) return;
  const int l = threadIdx.x & 63;
  const int sub = l / CPL;
  const int c = l % CPL;
  const int i = wv;
  float acc[8];
  {
    f16x8 v = *(const f16x8*)&X[(size_t)i * W + c * 8];
#pragma unroll
    for (int j = 0; j < 8; j++) acc[j] = (sub == 0) ? (float)v[j] : 0.f;
  }
  const int p0 = ptr[i];
  const int cnt = (int)deg[i] - 1;
  for (int e = 0; e < cnt; e += NB) {
    int idx = e + sub;
    int s = csr[p0 + (idx < cnt ? idx : cnt - 1)];
    f16x8 v = *(const f16x8*)&X[(size_t)s * W + c * 8];
    float m = (idx < cnt) ? 1.f : 0.f;
#pragma unroll
    for (int j = 0; j < 8; j++) acc[j] = fmaf(m, (float)v[j], acc[j]);
  }
#pragma unroll
  for (int mask = CPL; mask < 64; mask <<= 1) {
#pragma unroll
    for (int j = 0; j < 8; j++) acc[j] += __shfl_xor(acc[j], mask);
  }
  if (sub == 0) {
    float di = dis[i];
    f16x8 o;
#pragma unroll
    for (int j = 0; j < 8; j++) o[j] = (_Float16)(di * acc[j]);
    *(f16x8*)&Y[(size_t)i * W + c * 8] = o;
  }
}

// ---------------- MFMA f16 GEMM, NN=128, BM=128 (4 waves x 32 rows) -------
// MODE 0: Of16 = dis*tanh(v)   MODE 1: mean/lv/z fused   MODE 2: O1 = v (fp32)
template <int KT, int MODE>
__global__ __launch_bounds__(256) void k_gemm16(
    const _Float16* __restrict__ A1, int K1,
    const _Float16* __restrict__ A2, int K2,
    const unsigned short* __restrict__ Wp,
    const float* __restrict__ b1, const float* __restrict__ b2,
    float* __restrict__ O1, float* __restrict__ O2, float* __restrict__ O3,
    _Float16* __restrict__ Of16,
    const float* __restrict__ noise, const float* __restrict__ dis, int M) {
  __shared__ unsigned short wl[(KT / 8) * 1024];
  const int tid = threadIdx.x;
  const int l = tid & 63, wid = tid >> 6;
  const int row0 = blockIdx.x * 128;
  constexpr int totalU16 = (KT / 8) * 1024;
  for (int o = tid * 8; o < totalU16; o += 256 * 8) {
    *(uint4*)&wl[o] = *(const uint4*)&Wp[o];
  }
  __syncthreads();

  const int ar = l & 15, kg = l >> 4;
  f32x4 acc[2][8] = {};
  for (int k0 = 0; k0 < KT; k0 += 32) {
    const _Float16* Ab;
    int kl, Kb;
    if (k0 < K1) { Ab = A1; kl = k0; Kb = K1; }
    else         { Ab = A2; kl = k0 - K1; Kb = K2; }
    f16x8 a[2];
#pragma unroll
    for (int mt = 0; mt < 2; mt++) {
      int row = row0 + wid * 32 + mt * 16 + ar;
      if (row < M) {
        a[mt] = *(const f16x8*)&Ab[(size_t)row * Kb + kl + kg * 8];
      } else {
#pragma unroll
        for (int j = 0; j < 8; j++) a[mt][j] = (_Float16)0;
      }
    }
    int lb = ((k0 >> 3) + kg) * 1024 + ar * 8;
#pragma unroll
    for (int nt = 0; nt < 8; nt++) {
      f16x8 b = *(const f16x8*)&wl[lb + nt * 128];
#pragma unroll
      for (int mt = 0; mt < 2; mt++)
        acc[mt][nt] = __builtin_amdgcn_mfma_f32_16x16x32_f16(a[mt], b, acc[mt][nt], 0, 0, 0);
    }
  }

  // epilogue: D row = (l>>4)*4 + r, col = nt*16 + (l&15)
#pragma unroll
  for (int mt = 0; mt < 2; mt++) {
    int rbase = row0 + wid * 32 + mt * 16 + (l >> 4) * 4;
#pragma unroll
    for (int r = 0; r < 4; r++) {
      int rw = rbase + r;
      if (rw >= M) continue;
      if (MODE == 1) {
        float dr = dis[rw];
#pragma unroll
        for (int nt = 0; nt < 4; nt++) {
          int c = nt * 16 + (l & 15);
          float mv = acc[mt][nt][r] + b1[c];
          float lv = acc[mt][nt + 4][r] + b2[c];
          O1[(size_t)rw * 64 + c] = mv;
          O2[(size_t)rw * 64 + c] = lv;
          float z = noise[(size_t)rw * 64 + c] * expf(0.5f * lv) + mv;
          O3[(size_t)rw * 64 + c] = z;
          Of16[(size_t)rw * 64 + c] = (_Float16)(dr * z);
        }
      } else if (MODE == 0) {
        float dr = dis[rw];
#pragma unroll
        for (int nt = 0; nt < 8; nt++) {
          int c = nt * 16 + (l & 15);
          float v = tanhf(acc[mt][nt][r] + b1[c]);
          Of16[(size_t)rw * 128 + c] = (_Float16)(dr * v);
        }
      } else {
#pragma unroll
        for (int nt = 0; nt < 8; nt++) {
          int c = nt * 16 + (l & 15);
          O1[(size_t)rw * 128 + c] = acc[mt][nt][r] + b1[c];
        }
      }
    }
  }
}

// ---------------------------------------------------------------------------

static inline size_t align_up(size_t x, size_t a) { return (x + a - 1) & ~(a - 1); }

extern "C" void kernel_launch(void* const* d_in, const int* in_sizes, int n_in,
                              void* d_out, int out_size, void* d_ws, size_t ws_size,
                              hipStream_t stream) {
  const float* feature   = (const float*)d_in[0];
  const float* condition = (const float*)d_in[1];
  const float* noise     = (const float*)d_in[2];
  const int*   ei        = (const int*)d_in[3];
  const float* Wenc1 = (const float*)d_in[4];  const float* benc1 = (const float*)d_in[5];
  const float* Wenc2 = (const float*)d_in[6];  const float* benc2 = (const float*)d_in[7];
  const float* Wm    = (const float*)d_in[8];  const float* bm    = (const float*)d_in[9];
  const float* Wlv   = (const float*)d_in[10]; const float* blv   = (const float*)d_in[11];
  const float* Wd1   = (const float*)d_in[12]; const float* bd1   = (const float*)d_in[13];
  const float* Wd2   = (const float*)d_in[14]; const float* bd2   = (const float*)d_in[15];
  const float* Wout  = (const float*)d_in[16]; const float* bout  = (const float*)d_in[17];

  const int N = in_sizes[0] / FEAT;
  const int E = in_sizes[3] / 2;

  // ---- d_out segments ----
  float* out = (float*)d_out;
  float* zseg    = out;
  float* meanseg = out + (size_t)N * LAT;
  float* lvseg   = out + (size_t)2 * N * LAT;
  float* outseg  = out + (size_t)3 * N * LAT;  // fp32 [N,128]; scratch until final GEMM

  char* ob = (char*)outseg;
  _Float16* featF = (_Float16*)ob;                          // [N,128] f16
  uint* featFu = (uint*)featF;
  _Float16* condF = (_Float16*)(ob + (size_t)N * 128 * 2);  // [N,32] f16
  uint* condFu = (uint*)condF;
  _Float16* zf16 = (_Float16*)(ob + (size_t)N * 160 * 2);   // [N,64] f16

  // ---- workspace ----
  char* w = (char*)d_ws;
  size_t off = 0;
  float* deg    = (float*)(w + off); off = align_up(off + (size_t)N * 4, 256);
  float* dis    = (float*)(w + off); off = align_up(off + (size_t)N * 4, 256);
  int*   ptr    = (int*)(w + off);   off = align_up(off + (size_t)N * 4, 256);
  int*   cursor = (int*)(w + off);   off = align_up(off + (size_t)N * 4, 256);
  int*   blkSum = (int*)(w + off);   off = align_up(off + 4096, 256);
  int*   blkOff = (int*)(w + off);   off = align_up(off + 4096, 256);
  int*   csr    = (int*)(w + off);   off = align_up(off + (size_t)(E + 64) * 4, 256);
  unsigned short* WpE1 = (unsigned short*)(w + off); off = align_up(off + 160 * 128 * 2, 256);
  unsigned short* WpE2 = (unsigned short*)(w + off); off = align_up(off + 128 * 128 * 2, 256);
  unsigned short* WpML = (unsigned short*)(w + off); off = align_up(off + 128 * 128 * 2, 256);
  unsigned short* WpD1 = (unsigned short*)(w + off); off = align_up(off + 96 * 128 * 2, 256);
  unsigned short* WpD2 = (unsigned short*)(w + off); off = align_up(off + 128 * 128 * 2, 256);
  unsigned short* WpO  = (unsigned short*)(w + off); off = align_up(off + 128 * 128 * 2, 256);
  _Float16* S  = (_Float16*)(w + off); off = align_up(off + (size_t)N * 32 * 2, 256);
  _Float16* T1 = (_Float16*)(w + off); off = align_up(off + (size_t)N * 128 * 2, 256);
  _Float16* T2 = (_Float16*)(w + off); off = align_up(off + (size_t)N * 128 * 2, 256);

  const int TB = 256;
  dim3 blk(TB);
  dim3 gN((N + TB - 1) / TB);
  const int nScanBlk = (N + 1023) / 1024;
  dim3 gAgg((N + 3) / 4);
  dim3 gG((N + 127) / 128);
  dim3 gPart(8 * 2048);  // 8 groups x 2048 blocks, grid-stride over E

  // ---- prep ----
  k_init<<<gN, blk, 0, stream>>>(deg, N);
  k_count8<<<gPart, blk, 0, stream>>>(ei + E, deg, E, N);
  k_scan1<<<dim3(nScanBlk), blk, 0, stream>>>(deg, dis, ptr, blkSum, N);
  k_scan2<<<dim3(1), blk, 0, stream>>>(blkSum, blkOff, nScanBlk);
  k_scan3<<<gN, blk, 0, stream>>>(ptr, blkOff, cursor, N);
  k_fill8<<<gPart, blk, 0, stream>>>(ei, ptr, cursor, csr, E, N);

  // ---- casts + weight packing ----
  k_cast<7><<<dim3(((size_t)N * 128 / 4 + TB - 1) / TB), blk, 0, stream>>>(
      feature, featFu, dis, N * 128 / 4);
  k_cast<5><<<dim3(((size_t)N * 32 / 4 + TB - 1) / TB), blk, 0, stream>>>(
      condition, condFu, dis, N * 32 / 4);
  {
    PWArr pa;
    pa.d[0] = {Wenc1, WpE1, 160, 128, 0, 128};
    pa.d[1] = {Wenc2, WpE2, 128, 128, 0, 128};
    pa.d[2] = {Wm,    WpML, 128, 64,  0, 128};
    pa.d[3] = {Wlv,   WpML, 128, 64, 64, 128};
    pa.d[4] = {Wd1,   WpD1,  96, 128, 0, 128};
    pa.d[5] = {Wd2,   WpD2, 128, 128, 0, 128};
    pa.d[6] = {Wout,  WpO,  128, 128, 0, 128};
    k_packw<<<dim3(80, 7), blk, 0, stream>>>(pa);
  }

  // ---- encoder ----
  k_aggh<FEAT><<<gAgg, blk, 0, stream>>>(featF, T1, deg, dis, ptr, csr, N);
  k_aggh<COND><<<gAgg, blk, 0, stream>>>(condF, S, deg, dis, ptr, csr, N);
  k_gemm16<160, 0><<<gG, blk, 0, stream>>>(
      T1, FEAT, S, COND, WpE1, benc1, nullptr,
      nullptr, nullptr, nullptr, T2, nullptr, dis, N);
  k_aggh<HID><<<gAgg, blk, 0, stream>>>(T2, T1, deg, dis, ptr, csr, N);
  k_gemm16<128, 0><<<gG, blk, 0, stream>>>(
      T1, HID, nullptr, 0, WpE2, benc2, nullptr,
      nullptr, nullptr, nullptr, T2, nullptr, dis, N);
  k_aggh<HID><<<gAgg, blk, 0, stream>>>(T2, T1, deg, dis, ptr, csr, N);
  k_gemm16<128, 1><<<gG, blk, 0, stream>>>(
      T1, HID, nullptr, 0, WpML, bm, blv,
      meanseg, lvseg, zseg, zf16, noise, dis, N);

  // ---- decoder ----
  k_aggh<LAT><<<gAgg, blk, 0, stream>>>(zf16, T1, deg, dis, ptr, csr, N);
  k_gemm16<96, 0><<<gG, blk, 0, stream>>>(
      T1, LAT, S, COND, WpD1, bd1, nullptr,
      nullptr, nullptr, nullptr, T2, nullptr, dis, N);
  k_aggh<HID><<<gAgg, blk, 0, stream>>>(T2, T1, deg, dis, ptr, csr, N);
  k_gemm16<128, 0><<<gG, blk, 0, stream>>>(
      T1, HID, nullptr, 0, WpD2, bd2, nullptr,
      nullptr, nullptr, nullptr, T2, nullptr, dis, N);
  k_aggh<HID><<<gAgg, blk, 0, stream>>>(T2, T1, deg, dis, ptr, csr, N);
  k_gemm16<128, 2><<<gG, blk, 0, stream>>>(
      T1, HID, nullptr, 0, WpO, bout, nullptr,
      outseg, nullptr, nullptr, nullptr, nullptr, dis, N);
}

// Round 4
// 753.283 us; speedup vs baseline: 1.9472x; 1.1201x over previous
//
#include <hip/hip_runtime.h>
#include <hip/hip_fp16.h>
#include <math.h>

// ---------------------------------------------------------------------------
// CombinedHiddenGCVAE — round 4:
//  - Atomic-free CSR build: per-block LDS histograms -> partial-count slab ->
//    column-prefix cursors -> LDS-cursor fill. No global atomics at all.
//  - Mult-first encoder layer 1 (GEMM on raw fp32, agg with bias+tanh epilogue)
//  - Branch-guarded gather tails (no junk loads), in-place GEMM epilogues.
// ---------------------------------------------------------------------------

#define FEAT 128
#define COND 32
#define HID  128
#define LAT  64

#define NG    8       // dst-range groups (== XCDs)
#define RANGE 12500   // nodes per group (N=100000)
#define BPG   32      // blocks per group

typedef _Float16 f16x8 __attribute__((ext_vector_type(8)));
typedef float f32x4 __attribute__((ext_vector_type(4)));

__device__ __forceinline__ uint pk2(float x, float y) {
  __half2 h = __floats2half2_rn(x, y);
  return __builtin_bit_cast(uint, h);
}

// ---------------- prep: LDS histogram -> partial counts ----------------
// grid = NG*BPG blocks; block (g,bi) histograms dst[] over its E-slice for
// dst in [g*RANGE,(g+1)*RANGE), then stores counts to part[g*BPG+bi][*].
__global__ __launch_bounds__(256) void k_hist(const int* __restrict__ dstArr,
                                              int* __restrict__ part, int E, int n) {
  __shared__ int bins[RANGE];
  const int g = blockIdx.x & (NG - 1), bi = blockIdx.x >> 3;
  const int lo = g * RANGE;
  const int hi = min(n, lo + RANGE);
  for (int ii = threadIdx.x; ii < RANGE; ii += 256) bins[ii] = 0;
  __syncthreads();
  const int quads = E >> 2;
  const int per = (quads + BPG - 1) / BPG;
  const int q0 = bi * per, q1 = min(quads, q0 + per);
  const int4* d4 = (const int4*)dstArr;
  for (int q = q0 + threadIdx.x; q < q1; q += 256) {
    int4 d = d4[q];
    if (d.x >= lo && d.x < hi) atomicAdd(&bins[d.x - lo], 1);
    if (d.y >= lo && d.y < hi) atomicAdd(&bins[d.y - lo], 1);
    if (d.z >= lo && d.z < hi) atomicAdd(&bins[d.z - lo], 1);
    if (d.w >= lo && d.w < hi) atomicAdd(&bins[d.w - lo], 1);
  }
  if (bi == 0) {  // scalar tail (E not multiple of 4)
    for (int e = (quads << 2) + threadIdx.x; e < E; e += 256) {
      int d = dstArr[e];
      if (d >= lo && d < hi) atomicAdd(&bins[d - lo], 1);
    }
  }
  __syncthreads();
  int* dst = part + (size_t)(g * BPG + bi) * RANGE;
  for (int ii = threadIdx.x; ii < RANGE; ii += 256) dst[ii] = bins[ii];
}

// scan step 1: deg = sum of partials; dis = rsqrt(deg+1); ptr prefix of deg
__global__ void k_scan1(const int* __restrict__ part, int* __restrict__ degI,
                        float* __restrict__ dis, int* __restrict__ ptr,
                        int* __restrict__ blkSum, int n) {
  __shared__ int wtot[4];
  int tid = threadIdx.x, lane = tid & 63, wid = tid >> 6;
  int base = blockIdx.x * 1024 + tid * 4;
  int v[4];
#pragma unroll
  for (int j = 0; j < 4; j++) {
    int i = base + j;
    int c = 0;
    if (i < n) {
      int g = i / RANGE, ii = i - g * RANGE;
      const int* p = part + (size_t)g * BPG * RANGE + ii;
      for (int b = 0; b < BPG; b++) c += p[(size_t)b * RANGE];
      degI[i] = c;
      dis[i] = rsqrtf((float)(c + 1));
    }
    v[j] = c;
  }
  int tsum = v[0] + v[1] + v[2] + v[3];
  int x = tsum;
#pragma unroll
  for (int off = 1; off < 64; off <<= 1) {
    int y = __shfl_up(x, off);
    if (lane >= off) x += y;
  }
  if (lane == 63) wtot[wid] = x;
  __syncthreads();
  int wbase = 0;
  for (int w = 0; w < wid; w++) wbase += wtot[w];
  int run = wbase + (x - tsum);
#pragma unroll
  for (int j = 0; j < 4; j++) {
    int i = base + j;
    if (i < n) ptr[i] = run;
    run += v[j];
  }
  if (tid == blockDim.x - 1) blkSum[blockIdx.x] = wbase + x;
}

__global__ void k_scan2(const int* __restrict__ blkSum, int* __restrict__ blkOff, int nb) {
  __shared__ int wtot[4];
  int tid = threadIdx.x, lane = tid & 63, wid = tid >> 6;
  int v = (tid < nb) ? blkSum[tid] : 0;
  int x = v;
#pragma unroll
  for (int off = 1; off < 64; off <<= 1) {
    int y = __shfl_up(x, off);
    if (lane >= off) x += y;
  }
  if (lane == 63) wtot[wid] = x;
  __syncthreads();
  int wbase = 0;
  for (int w = 0; w < wid; w++) wbase += wtot[w];
  if (tid < nb) blkOff[tid] = wbase + x - v;
}

__global__ void k_scan3(int* __restrict__ ptr, const int* __restrict__ blkOff, int n) {
  int i = blockIdx.x * blockDim.x + threadIdx.x;
  if (i < n) ptr[i] += blkOff[i >> 10];
}

// column prefix over per-block partials + ptr -> per-block base cursors
__global__ void k_cum(int* __restrict__ part, const int* __restrict__ ptr, int n) {
  int i = blockIdx.x * blockDim.x + threadIdx.x;
  if (i >= n) return;
  int g = i / RANGE, ii = i - g * RANGE;
  int* p = part + (size_t)g * BPG * RANGE + ii;
  int run = ptr[i];
  for (int b = 0; b < BPG; b++) {
    int t = p[(size_t)b * RANGE];
    p[(size_t)b * RANGE] = run;
    run += t;
  }
}

// LDS-cursor CSR fill; identical slicing to k_hist
__global__ __launch_bounds__(256) void k_fill2(const int* __restrict__ ei,
                                               const int* __restrict__ part,
                                               int* __restrict__ csr, int E, int n) {
  __shared__ int cur[RANGE];
  const int g = blockIdx.x & (NG - 1), bi = blockIdx.x >> 3;
  const int lo = g * RANGE;
  const int hi = min(n, lo + RANGE);
  const int* base = part + (size_t)(g * BPG + bi) * RANGE;
  for (int ii = threadIdx.x; ii < RANGE; ii += 256) cur[ii] = base[ii];
  __syncthreads();
  const int quads = E >> 2;
  const int per = (quads + BPG - 1) / BPG;
  const int q0 = bi * per, q1 = min(quads, q0 + per);
  const int4* s4 = (const int4*)ei;
  const int4* d4 = (const int4*)(ei + E);
  for (int q = q0 + threadIdx.x; q < q1; q += 256) {
    int4 s = s4[q], d = d4[q];
    if (d.x >= lo && d.x < hi) csr[atomicAdd(&cur[d.x - lo], 1)] = s.x;
    if (d.y >= lo && d.y < hi) csr[atomicAdd(&cur[d.y - lo], 1)] = s.y;
    if (d.z >= lo && d.z < hi) csr[atomicAdd(&cur[d.z - lo], 1)] = s.z;
    if (d.w >= lo && d.w < hi) csr[atomicAdd(&cur[d.w - lo], 1)] = s.w;
  }
  if (bi == 0) {
    for (int e = (quads << 2) + threadIdx.x; e < E; e += 256) {
      int d = ei[E + e];
      if (d >= lo && d < hi) csr[atomicAdd(&cur[d - lo], 1)] = ei[e];
    }
  }
}

// ---------------- fp32 -> f16 cast with dis prescale ----------------
template <int LW>
__global__ void k_cast(const float* __restrict__ src, uint* __restrict__ dst,
                       const float* __restrict__ dis, int n4) {
  int t = blockIdx.x * blockDim.x + threadIdx.x;
  if (t >= n4) return;
  size_t i4 = (size_t)t * 4;
  int row = (int)(i4 >> LW);
  float d = dis[row];
  float4 v = *(const float4*)&src[i4];
  uint2 o;
  o.x = pk2(d * v.x, d * v.y);
  o.y = pk2(d * v.z, d * v.w);
  *(uint2*)&dst[t * 2] = o;
}

// ---------------- weight pack: fp32 [K,N] -> f16 fragment layout ----------
struct PW { const float* src; unsigned short* dst; int K, Ncols, colOff, NnTot; };
struct PWArr { PW d[7]; };

__global__ void k_packw(PWArr a) {
  PW d = a.d[blockIdx.y];
  int t = blockIdx.x * blockDim.x + threadIdx.x;
  if (t >= d.K * d.Ncols) return;
  int k = t / d.Ncols;
  int n = t - k * d.Ncols;
  float v = d.src[t];
  d.dst[((size_t)(k >> 3) * d.NnTot + d.colOff + n) * 8 + (k & 7)] =
      __builtin_bit_cast(unsigned short, (_Float16)v);
}

// ---------------- aggregation over pre-scaled f16 rows --------------------
// acc = X[i] + sum_nbr X[s]  (all rows pre-scaled by dis[src])
// EPI 0: Y = dis_i*acc            (plain agg value, f16)
// EPI 1: Y = dis_i*tanh(dis_i*acc + bias[col])  (fused conv epilogue, prescaled)
template <int W, int EPI>
__global__ __launch_bounds__(256) void k_aggh(
    const _Float16* __restrict__ X, _Float16* __restrict__ Y,
    const int* __restrict__ degI, const float* __restrict__ dis,
    const int* __restrict__ ptr, const int* __restrict__ csr,
    const float* __restrict__ bias, int n) {
  constexpr int CPL = W / 8;   // lanes per row (16B each)
  constexpr int NB = 64 / CPL; // rows in flight
  int wv = blockIdx.x * 4 + (threadIdx.x >> 6);
  if (wv >= n) return;
  const int l = threadIdx.x & 63;
  const int sub = l / CPL;
  const int c = l % CPL;
  const int i = wv;
  float acc[8];
  {
    f16x8 v = *(const f16x8*)&X[(size_t)i * W + c * 8];
#pragma unroll
    for (int j = 0; j < 8; j++) acc[j] = (sub == 0) ? (float)v[j] : 0.f;
  }
  const int p0 = ptr[i];
  const int cnt = degI[i];
  for (int e = 0; e < cnt; e += NB) {
    int idx = e + sub;
    if (idx < cnt) {
      int s = csr[p0 + idx];
      f16x8 v = *(const f16x8*)&X[(size_t)s * W + c * 8];
#pragma unroll
      for (int j = 0; j < 8; j++) acc[j] += (float)v[j];
    }
  }
#pragma unroll
  for (int mask = CPL; mask < 64; mask <<= 1) {
#pragma unroll
    for (int j = 0; j < 8; j++) acc[j] += __shfl_xor(acc[j], mask);
  }
  if (sub == 0) {
    float di = dis[i];
    f16x8 o;
    if (EPI == 1) {
      float4 ba = *(const float4*)&bias[c * 8];
      float4 bb = *(const float4*)&bias[c * 8 + 4];
      float bv[8] = {ba.x, ba.y, ba.z, ba.w, bb.x, bb.y, bb.z, bb.w};
#pragma unroll
      for (int j = 0; j < 8; j++)
        o[j] = (_Float16)(di * tanhf(di * acc[j] + bv[j]));
    } else {
#pragma unroll
      for (int j = 0; j < 8; j++) o[j] = (_Float16)(di * acc[j]);
    }
    *(f16x8*)&Y[(size_t)i * W + c * 8] = o;
  }
}

// ---------------- MFMA f16 GEMM, NN=128, BM=128 (4 waves x 32 rows) -------
// MODE 0: Of16 = dis*tanh(v+b1)   (in-place on A allowed: block-local rows)
// MODE 1: mean/lv/z fused (width 64 outputs)
// MODE 2: O1 = v+b1 (fp32 final out)
template <int KT, int MODE>
__global__ __launch_bounds__(256) void k_gemm16(
    const _Float16* A1, int K1,
    const _Float16* __restrict__ A2, int K2,
    const unsigned short* __restrict__ Wp,
    const float* __restrict__ b1, const float* __restrict__ b2,
    float* __restrict__ O1, float* __restrict__ O2, float* __restrict__ O3,
    _Float16* Of16,
    const float* __restrict__ noise, const float* __restrict__ dis, int M) {
  __shared__ unsigned short wl[(KT / 8) * 1024];
  const int tid = threadIdx.x;
  const int l = tid & 63, wid = tid >> 6;
  const int row0 = blockIdx.x * 128;
  constexpr int totalU16 = (KT / 8) * 1024;
  for (int o = tid * 8; o < totalU16; o += 256 * 8) {
    *(uint4*)&wl[o] = *(const uint4*)&Wp[o];
  }
  __syncthreads();

  const int ar = l & 15, kg = l >> 4;
  f32x4 acc[2][8] = {};
  for (int k0 = 0; k0 < KT; k0 += 32) {
    const _Float16* Ab;
    int kl, Kb;
    if (k0 < K1) { Ab = A1; kl = k0; Kb = K1; }
    else         { Ab = A2; kl = k0 - K1; Kb = K2; }
    f16x8 a[2];
#pragma unroll
    for (int mt = 0; mt < 2; mt++) {
      int row = row0 + wid * 32 + mt * 16 + ar;
      if (row < M) {
        a[mt] = *(const f16x8*)&Ab[(size_t)row * Kb + kl + kg * 8];
      } else {
#pragma unroll
        for (int j = 0; j < 8; j++) a[mt][j] = (_Float16)0;
      }
    }
    int lb = ((k0 >> 3) + kg) * 1024 + ar * 8;
#pragma unroll
    for (int nt = 0; nt < 8; nt++) {
      f16x8 b = *(const f16x8*)&wl[lb + nt * 128];
#pragma unroll
      for (int mt = 0; mt < 2; mt++)
        acc[mt][nt] = __builtin_amdgcn_mfma_f32_16x16x32_f16(a[mt], b, acc[mt][nt], 0, 0, 0);
    }
  }

#pragma unroll
  for (int mt = 0; mt < 2; mt++) {
    int rbase = row0 + wid * 32 + mt * 16 + (l >> 4) * 4;
#pragma unroll
    for (int r = 0; r < 4; r++) {
      int rw = rbase + r;
      if (rw >= M) continue;
      if (MODE == 1) {
        float dr = dis[rw];
#pragma unroll
        for (int nt = 0; nt < 4; nt++) {
          int c = nt * 16 + (l & 15);
          float mv = acc[mt][nt][r] + b1[c];
          float lv = acc[mt][nt + 4][r] + b2[c];
          O1[(size_t)rw * 64 + c] = mv;
          O2[(size_t)rw * 64 + c] = lv;
          float z = noise[(size_t)rw * 64 + c] * expf(0.5f * lv) + mv;
          O3[(size_t)rw * 64 + c] = z;
          Of16[(size_t)rw * 64 + c] = (_Float16)(dr * z);
        }
      } else if (MODE == 0) {
        float dr = dis[rw];
#pragma unroll
        for (int nt = 0; nt < 8; nt++) {
          int c = nt * 16 + (l & 15);
          float v = tanhf(acc[mt][nt][r] + b1[c]);
          Of16[(size_t)rw * 128 + c] = (_Float16)(dr * v);
        }
      } else {
#pragma unroll
        for (int nt = 0; nt < 8; nt++) {
          int c = nt * 16 + (l & 15);
          O1[(size_t)rw * 128 + c] = acc[mt][nt][r] + b1[c];
        }
      }
    }
  }
}

// ---------------- P1 GEMM: fp32 [feat|cond] inputs, prescaled f16 out -----
__global__ __launch_bounds__(256) void k_gemmP1(
    const float* __restrict__ F, const float* __restrict__ Cnd,
    const unsigned short* __restrict__ Wp, _Float16* __restrict__ O,
    const float* __restrict__ dis, int M) {
  __shared__ unsigned short wl[20 * 1024];  // K=160
  const int tid = threadIdx.x;
  const int l = tid & 63, wid = tid >> 6;
  const int row0 = blockIdx.x * 128;
  for (int o = tid * 8; o < 20 * 1024; o += 256 * 8) {
    *(uint4*)&wl[o] = *(const uint4*)&Wp[o];
  }
  __syncthreads();

  const int ar = l & 15, kg = l >> 4;
  f32x4 acc[2][8] = {};
  for (int k0 = 0; k0 < 160; k0 += 32) {
    int col0 = k0 + kg * 8;
    f16x8 a[2];
#pragma unroll
    for (int mt = 0; mt < 2; mt++) {
      int row = row0 + wid * 32 + mt * 16 + ar;
      float4 u = {0, 0, 0, 0}, v = {0, 0, 0, 0};
      if (row < M) {
        if (col0 < 128) {
          u = *(const float4*)&F[(size_t)row * 128 + col0];
          v = *(const float4*)&F[(size_t)row * 128 + col0 + 4];
        } else {
          u = *(const float4*)&Cnd[(size_t)row * 32 + (col0 - 128)];
          v = *(const float4*)&Cnd[(size_t)row * 32 + (col0 - 124)];
        }
      }
      a[mt][0] = (_Float16)u.x; a[mt][1] = (_Float16)u.y;
      a[mt][2] = (_Float16)u.z; a[mt][3] = (_Float16)u.w;
      a[mt][4] = (_Float16)v.x; a[mt][5] = (_Float16)v.y;
      a[mt][6] = (_Float16)v.z; a[mt][7] = (_Float16)v.w;
    }
    int lb = ((k0 >> 3) + kg) * 1024 + ar * 8;
#pragma unroll
    for (int nt = 0; nt < 8; nt++) {
      f16x8 b = *(const f16x8*)&wl[lb + nt * 128];
#pragma unroll
      for (int mt = 0; mt < 2; mt++)
        acc[mt][nt] = __builtin_amdgcn_mfma_f32_16x16x32_f16(a[mt], b, acc[mt][nt], 0, 0, 0);
    }
  }
#pragma unroll
  for (int mt = 0; mt < 2; mt++) {
    int rbase = row0 + wid * 32 + mt * 16 + (l >> 4) * 4;
#pragma unroll
    for (int r = 0; r < 4; r++) {
      int rw = rbase + r;
      if (rw >= M) continue;
      float dr = dis[rw];
#pragma unroll
      for (int nt = 0; nt < 8; nt++) {
        int c = nt * 16 + (l & 15);
        O[(size_t)rw * 128 + c] = (_Float16)(dr * acc[mt][nt][r]);
      }
    }
  }
}

// ---------------------------------------------------------------------------

static inline size_t align_up(size_t x, size_t a) { return (x + a - 1) & ~(a - 1); }

extern "C" void kernel_launch(void* const* d_in, const int* in_sizes, int n_in,
                              void* d_out, int out_size, void* d_ws, size_t ws_size,
                              hipStream_t stream) {
  const float* feature   = (const float*)d_in[0];
  const float* condition = (const float*)d_in[1];
  const float* noise     = (const float*)d_in[2];
  const int*   ei        = (const int*)d_in[3];
  const float* Wenc1 = (const float*)d_in[4];  const float* benc1 = (const float*)d_in[5];
  const float* Wenc2 = (const float*)d_in[6];  const float* benc2 = (const float*)d_in[7];
  const float* Wm    = (const float*)d_in[8];  const float* bm    = (const float*)d_in[9];
  const float* Wlv   = (const float*)d_in[10]; const float* blv   = (const float*)d_in[11];
  const float* Wd1   = (const float*)d_in[12]; const float* bd1   = (const float*)d_in[13];
  const float* Wd2   = (const float*)d_in[14]; const float* bd2   = (const float*)d_in[15];
  const float* Wout  = (const float*)d_in[16]; const float* bout  = (const float*)d_in[17];

  const int N = in_sizes[0] / FEAT;
  const int E = in_sizes[3] / 2;

  // ---- d_out segments ----
  float* out = (float*)d_out;
  float* zseg    = out;
  float* meanseg = out + (size_t)N * LAT;
  float* lvseg   = out + (size_t)2 * N * LAT;
  float* outseg  = out + (size_t)3 * N * LAT;  // fp32 [N,128]; scratch until final GEMM

  // staging aliased into outseg (dead before final GEMM writes it):
  char* ob = (char*)outseg;
  _Float16* zf16  = (_Float16*)ob;                          // [N,64]  prescaled z
  _Float16* condC = (_Float16*)(ob + (size_t)N * 64 * 2);   // [N,32]  prescaled cond
  uint* condCu = (uint*)condC;

  // ---- workspace ----
  char* w = (char*)d_ws;
  size_t off = 0;
  int*   degI   = (int*)(w + off);   off = align_up(off + (size_t)N * 4, 256);
  float* dis    = (float*)(w + off); off = align_up(off + (size_t)N * 4, 256);
  int*   ptr    = (int*)(w + off);   off = align_up(off + (size_t)N * 4, 256);
  int*   blkSum = (int*)(w + off);   off = align_up(off + 4096, 256);
  int*   blkOff = (int*)(w + off);   off = align_up(off + 4096, 256);
  int*   csr    = (int*)(w + off);   off = align_up(off + (size_t)(E + 64) * 4, 256);
  unsigned short* WpE1 = (unsigned short*)(w + off); off = align_up(off + 160 * 128 * 2, 256);
  unsigned short* WpE2 = (unsigned short*)(w + off); off = align_up(off + 128 * 128 * 2, 256);
  unsigned short* WpML = (unsigned short*)(w + off); off = align_up(off + 128 * 128 * 2, 256);
  unsigned short* WpD1 = (unsigned short*)(w + off); off = align_up(off + 96 * 128 * 2, 256);
  unsigned short* WpD2 = (unsigned short*)(w + off); off = align_up(off + 128 * 128 * 2, 256);
  unsigned short* WpO  = (unsigned short*)(w + off); off = align_up(off + 128 * 128 * 2, 256);
  _Float16* S  = (_Float16*)(w + off); off = align_up(off + (size_t)N * 32 * 2, 256);
  _Float16* TA = (_Float16*)(w + off); off = align_up(off + (size_t)N * 128 * 2, 256);
  _Float16* TB = (_Float16*)(w + off); off = align_up(off + (size_t)N * 128 * 2, 256);
  // partial-count slab aliases the first 12.8 MB of TA (dead before TA written)
  int* part = (int*)TA;  // [NG*BPG][RANGE]

  const int TB_ = 256;
  dim3 blk(TB_);
  dim3 gN((N + TB_ - 1) / TB_);
  const int nScanBlk = (N + 1023) / 1024;
  dim3 gAgg((N + 3) / 4);
  dim3 gG((N + 127) / 128);
  dim3 gPart(NG * BPG);

  // ---- graph prep (no global atomics) ----
  k_hist<<<gPart, blk, 0, stream>>>(ei + E, part, E, N);
  k_scan1<<<dim3(nScanBlk), blk, 0, stream>>>(part, degI, dis, ptr, blkSum, N);
  k_scan2<<<dim3(1), blk, 0, stream>>>(blkSum, blkOff, nScanBlk);
  k_scan3<<<gN, blk, 0, stream>>>(ptr, blkOff, N);
  k_cum<<<gN, blk, 0, stream>>>(part, ptr, N);
  k_fill2<<<gPart, blk, 0, stream>>>(ei, part, csr, E, N);

  // ---- cond cast + weight packing ----
  k_cast<5><<<dim3(((size_t)N * 32 / 4 + TB_ - 1) / TB_), blk, 0, stream>>>(
      condition, condCu, dis, N * 32 / 4);
  {
    PWArr pa;
    pa.d[0] = {Wenc1, WpE1, 160, 128, 0, 128};
    pa.d[1] = {Wenc2, WpE2, 128, 128, 0, 128};
    pa.d[2] = {Wm,    WpML, 128, 64,  0, 128};
    pa.d[3] = {Wlv,   WpML, 128, 64, 64, 128};
    pa.d[4] = {Wd1,   WpD1,  96, 128, 0, 128};
    pa.d[5] = {Wd2,   WpD2, 128, 128, 0, 128};
    pa.d[6] = {Wout,  WpO,  128, 128, 0, 128};
    k_packw<<<dim3(80, 7), blk, 0, stream>>>(pa);
  }

  // ---- encoder ----
  // P1 = [feat|cond] @ Wenc1 (mult-first), prescaled f16 -> TA
  k_gemmP1<<<gG, blk, 0, stream>>>(feature, condition, WpE1, TA, dis, N);
  // h1' = dis*tanh(agg(P1) + b1) -> TB (agg epilogue)
  k_aggh<HID, 1><<<gAgg, blk, 0, stream>>>(TA, TB, degI, dis, ptr, csr, benc1, N);
  // h2' : agg(h1') -> TA ; GEMM in place TA -> TA
  k_aggh<HID, 0><<<gAgg, blk, 0, stream>>>(TB, TA, degI, dis, ptr, csr, nullptr, N);
  k_gemm16<128, 0><<<gG, blk, 0, stream>>>(
      TA, HID, nullptr, 0, WpE2, benc2, nullptr,
      nullptr, nullptr, nullptr, TA, nullptr, dis, N);
  // mean/lv/z : agg(h2') -> TB ; fused ML GEMM
  k_aggh<HID, 0><<<gAgg, blk, 0, stream>>>(TA, TB, degI, dis, ptr, csr, nullptr, N);
  k_gemm16<128, 1><<<gG, blk, 0, stream>>>(
      TB, HID, nullptr, 0, WpML, bm, blv,
      meanseg, lvseg, zseg, zf16, noise, dis, N);

  // ---- decoder ----
  k_aggh<COND, 0><<<gAgg, blk, 0, stream>>>(condC, S, degI, dis, ptr, csr, nullptr, N);
  k_aggh<LAT, 0><<<gAgg, blk, 0, stream>>>(zf16, TA, degI, dis, ptr, csr, nullptr, N);
  k_gemm16<96, 0><<<gG, blk, 0, stream>>>(
      TA, LAT, S, COND, WpD1, bd1, nullptr,
      nullptr, nullptr, nullptr, TB, nullptr, dis, N);  // g1' -> TB
  k_aggh<HID, 0><<<gAgg, blk, 0, stream>>>(TB, TA, degI, dis, ptr, csr, nullptr, N);
  k_gemm16<128, 0><<<gG, blk, 0, stream>>>(
      TA, HID, nullptr, 0, WpD2, bd2, nullptr,
      nullptr, nullptr, nullptr, TA, nullptr, dis, N);  // g2' in place
  k_aggh<HID, 0><<<gAgg, blk, 0, stream>>>(TA, TB, degI, dis, ptr, csr, nullptr, N);
  k_gemm16<128, 2><<<gG, blk, 0, stream>>>(
      TB, HID, nullptr, 0, WpO, bout, nullptr,
      outseg, nullptr, nullptr, nullptr, nullptr, dis, N);
}

// Round 5
// 692.344 us; speedup vs baseline: 2.1186x; 1.0880x over previous
//
#include <hip/hip_runtime.h>
#include <hip/hip_fp16.h>
#include <math.h>

// ---------------------------------------------------------------------------
// CombinedHiddenGCVAE — round 5:
//  - k_aggh inner loop: packed-f16 accumulation (v_pk_add_f16, 4 ops/row vs
//    16 cvt+add) + 2x unrolled gathers (2 loads in flight per lane).
//    f32 conversion + shfl reduce happens once per node.
//  - Rest identical to round 4 (atomic-free CSR build, mult-first layer 1,
//    fused epilogues, in-place GEMMs).
// ---------------------------------------------------------------------------

#define FEAT 128
#define COND 32
#define HID  128
#define LAT  64

#define NG    8       // dst-range groups (== XCDs)
#define RANGE 12500   // nodes per group (N=100000)
#define BPG   32      // blocks per group

typedef _Float16 f16x8 __attribute__((ext_vector_type(8)));
typedef float f32x4 __attribute__((ext_vector_type(4)));

__device__ __forceinline__ uint pk2(float x, float y) {
  __half2 h = __floats2half2_rn(x, y);
  return __builtin_bit_cast(uint, h);
}

// ---------------- prep: LDS histogram -> partial counts ----------------
__global__ __launch_bounds__(256) void k_hist(const int* __restrict__ dstArr,
                                              int* __restrict__ part, int E, int n) {
  __shared__ int bins[RANGE];
  const int g = blockIdx.x & (NG - 1), bi = blockIdx.x >> 3;
  const int lo = g * RANGE;
  const int hi = min(n, lo + RANGE);
  for (int ii = threadIdx.x; ii < RANGE; ii += 256) bins[ii] = 0;
  __syncthreads();
  const int quads = E >> 2;
  const int per = (quads + BPG - 1) / BPG;
  const int q0 = bi * per, q1 = min(quads, q0 + per);
  const int4* d4 = (const int4*)dstArr;
  for (int q = q0 + threadIdx.x; q < q1; q += 256) {
    int4 d = d4[q];
    if (d.x >= lo && d.x < hi) atomicAdd(&bins[d.x - lo], 1);
    if (d.y >= lo && d.y < hi) atomicAdd(&bins[d.y - lo], 1);
    if (d.z >= lo && d.z < hi) atomicAdd(&bins[d.z - lo], 1);
    if (d.w >= lo && d.w < hi) atomicAdd(&bins[d.w - lo], 1);
  }
  if (bi == 0) {
    for (int e = (quads << 2) + threadIdx.x; e < E; e += 256) {
      int d = dstArr[e];
      if (d >= lo && d < hi) atomicAdd(&bins[d - lo], 1);
    }
  }
  __syncthreads();
  int* dst = part + (size_t)(g * BPG + bi) * RANGE;
  for (int ii = threadIdx.x; ii < RANGE; ii += 256) dst[ii] = bins[ii];
}

// scan step 1: deg = sum of partials; dis = rsqrt(deg+1); ptr prefix of deg
__global__ void k_scan1(const int* __restrict__ part, int* __restrict__ degI,
                        float* __restrict__ dis, int* __restrict__ ptr,
                        int* __restrict__ blkSum, int n) {
  __shared__ int wtot[4];
  int tid = threadIdx.x, lane = tid & 63, wid = tid >> 6;
  int base = blockIdx.x * 1024 + tid * 4;
  int v[4];
#pragma unroll
  for (int j = 0; j < 4; j++) {
    int i = base + j;
    int c = 0;
    if (i < n) {
      int g = i / RANGE, ii = i - g * RANGE;
      const int* p = part + (size_t)g * BPG * RANGE + ii;
      for (int b = 0; b < BPG; b++) c += p[(size_t)b * RANGE];
      degI[i] = c;
      dis[i] = rsqrtf((float)(c + 1));
    }
    v[j] = c;
  }
  int tsum = v[0] + v[1] + v[2] + v[3];
  int x = tsum;
#pragma unroll
  for (int off = 1; off < 64; off <<= 1) {
    int y = __shfl_up(x, off);
    if (lane >= off) x += y;
  }
  if (lane == 63) wtot[wid] = x;
  __syncthreads();
  int wbase = 0;
  for (int w = 0; w < wid; w++) wbase += wtot[w];
  int run = wbase + (x - tsum);
#pragma unroll
  for (int j = 0; j < 4; j++) {
    int i = base + j;
    if (i < n) ptr[i] = run;
    run += v[j];
  }
  if (tid == blockDim.x - 1) blkSum[blockIdx.x] = wbase + x;
}

__global__ void k_scan2(const int* __restrict__ blkSum, int* __restrict__ blkOff, int nb) {
  __shared__ int wtot[4];
  int tid = threadIdx.x, lane = tid & 63, wid = tid >> 6;
  int v = (tid < nb) ? blkSum[tid] : 0;
  int x = v;
#pragma unroll
  for (int off = 1; off < 64; off <<= 1) {
    int y = __shfl_up(x, off);
    if (lane >= off) x += y;
  }
  if (lane == 63) wtot[wid] = x;
  __syncthreads();
  int wbase = 0;
  for (int w = 0; w < wid; w++) wbase += wtot[w];
  if (tid < nb) blkOff[tid] = wbase + x - v;
}

__global__ void k_scan3(int* __restrict__ ptr, const int* __restrict__ blkOff, int n) {
  int i = blockIdx.x * blockDim.x + threadIdx.x;
  if (i < n) ptr[i] += blkOff[i >> 10];
}

// column prefix over per-block partials + ptr -> per-block base cursors
__global__ void k_cum(int* __restrict__ part, const int* __restrict__ ptr, int n) {
  int i = blockIdx.x * blockDim.x + threadIdx.x;
  if (i >= n) return;
  int g = i / RANGE, ii = i - g * RANGE;
  int* p = part + (size_t)g * BPG * RANGE + ii;
  int run = ptr[i];
  for (int b = 0; b < BPG; b++) {
    int t = p[(size_t)b * RANGE];
    p[(size_t)b * RANGE] = run;
    run += t;
  }
}

// LDS-cursor CSR fill; identical slicing to k_hist
__global__ __launch_bounds__(256) void k_fill2(const int* __restrict__ ei,
                                               const int* __restrict__ part,
                                               int* __restrict__ csr, int E, int n) {
  __shared__ int cur[RANGE];
  const int g = blockIdx.x & (NG - 1), bi = blockIdx.x >> 3;
  const int lo = g * RANGE;
  const int hi = min(n, lo + RANGE);
  const int* base = part + (size_t)(g * BPG + bi) * RANGE;
  for (int ii = threadIdx.x; ii < RANGE; ii += 256) cur[ii] = base[ii];
  __syncthreads();
  const int quads = E >> 2;
  const int per = (quads + BPG - 1) / BPG;
  const int q0 = bi * per, q1 = min(quads, q0 + per);
  const int4* s4 = (const int4*)ei;
  const int4* d4 = (const int4*)(ei + E);
  for (int q = q0 + threadIdx.x; q < q1; q += 256) {
    int4 s = s4[q], d = d4[q];
    if (d.x >= lo && d.x < hi) csr[atomicAdd(&cur[d.x - lo], 1)] = s.x;
    if (d.y >= lo && d.y < hi) csr[atomicAdd(&cur[d.y - lo], 1)] = s.y;
    if (d.z >= lo && d.z < hi) csr[atomicAdd(&cur[d.z - lo], 1)] = s.z;
    if (d.w >= lo && d.w < hi) csr[atomicAdd(&cur[d.w - lo], 1)] = s.w;
  }
  if (bi == 0) {
    for (int e = (quads << 2) + threadIdx.x; e < E; e += 256) {
      int d = ei[E + e];
      if (d >= lo && d < hi) csr[atomicAdd(&cur[d - lo], 1)] = ei[e];
    }
  }
}

// ---------------- fp32 -> f16 cast with dis prescale ----------------
template <int LW>
__global__ void k_cast(const float* __restrict__ src, uint* __restrict__ dst,
                       const float* __restrict__ dis, int n4) {
  int t = blockIdx.x * blockDim.x + threadIdx.x;
  if (t >= n4) return;
  size_t i4 = (size_t)t * 4;
  int row = (int)(i4 >> LW);
  float d = dis[row];
  float4 v = *(const float4*)&src[i4];
  uint2 o;
  o.x = pk2(d * v.x, d * v.y);
  o.y = pk2(d * v.z, d * v.w);
  *(uint2*)&dst[t * 2] = o;
}

// ---------------- weight pack: fp32 [K,N] -> f16 fragment layout ----------
struct PW { const float* src; unsigned short* dst; int K, Ncols, colOff, NnTot; };
struct PWArr { PW d[7]; };

__global__ void k_packw(PWArr a) {
  PW d = a.d[blockIdx.y];
  int t = blockIdx.x * blockDim.x + threadIdx.x;
  if (t >= d.K * d.Ncols) return;
  int k = t / d.Ncols;
  int n = t - k * d.Ncols;
  float v = d.src[t];
  d.dst[((size_t)(k >> 3) * d.NnTot + d.colOff + n) * 8 + (k & 7)] =
      __builtin_bit_cast(unsigned short, (_Float16)v);
}

// ---------------- aggregation over pre-scaled f16 rows --------------------
// acc (packed f16) = X[i] + sum_nbr X[s]; f32 convert + reduce once per node.
// EPI 0: Y = dis_i*acc    EPI 1: Y = dis_i*tanh(dis_i*acc + bias[col])
template <int W, int EPI>
__global__ __launch_bounds__(256) void k_aggh(
    const _Float16* __restrict__ X, _Float16* __restrict__ Y,
    const int* __restrict__ degI, const float* __restrict__ dis,
    const int* __restrict__ ptr, const int* __restrict__ csr,
    const float* __restrict__ bias, int n) {
  constexpr int CPL = W / 8;   // lanes per row (16B each)
  constexpr int NB = 64 / CPL; // rows in flight per issue
  int wv = blockIdx.x * 4 + (threadIdx.x >> 6);
  if (wv >= n) return;
  const int l = threadIdx.x & 63;
  const int sub = l / CPL;
  const int c = l % CPL;
  const int i = wv;
  f16x8 accH;
  if (sub == 0) {
    accH = *(const f16x8*)&X[(size_t)i * W + c * 8];
  } else {
#pragma unroll
    for (int j = 0; j < 8; j++) accH[j] = (_Float16)0;
  }
  const int p0 = ptr[i];
  const int cnt = degI[i];
  int e = 0;
  // 2x unrolled main loop: two independent gathers in flight per lane
  for (; e + 2 * NB <= cnt; e += 2 * NB) {
    int s0 = csr[p0 + e + sub];
    int s1 = csr[p0 + e + NB + sub];
    f16x8 v0 = *(const f16x8*)&X[(size_t)s0 * W + c * 8];
    f16x8 v1 = *(const f16x8*)&X[(size_t)s1 * W + c * 8];
    accH += v0;
    accH += v1;
  }
  for (; e < cnt; e += NB) {
    int idx = e + sub;
    if (idx < cnt) {
      int s = csr[p0 + idx];
      accH += *(const f16x8*)&X[(size_t)s * W + c * 8];
    }
  }
  // single f32 conversion + cross-subgroup reduce
  float acc[8];
#pragma unroll
  for (int j = 0; j < 8; j++) acc[j] = (float)accH[j];
#pragma unroll
  for (int mask = CPL; mask < 64; mask <<= 1) {
#pragma unroll
    for (int j = 0; j < 8; j++) acc[j] += __shfl_xor(acc[j], mask);
  }
  if (sub == 0) {
    float di = dis[i];
    f16x8 o;
    if (EPI == 1) {
      float4 ba = *(const float4*)&bias[c * 8];
      float4 bb = *(const float4*)&bias[c * 8 + 4];
      float bv[8] = {ba.x, ba.y, ba.z, ba.w, bb.x, bb.y, bb.z, bb.w};
#pragma unroll
      for (int j = 0; j < 8; j++)
        o[j] = (_Float16)(di * tanhf(di * acc[j] + bv[j]));
    } else {
#pragma unroll
      for (int j = 0; j < 8; j++) o[j] = (_Float16)(di * acc[j]);
    }
    *(f16x8*)&Y[(size_t)i * W + c * 8] = o;
  }
}

// ---------------- MFMA f16 GEMM, NN=128, BM=128 (4 waves x 32 rows) -------
// MODE 0: Of16 = dis*tanh(v+b1)   MODE 1: mean/lv/z fused   MODE 2: O1 = v+b1
template <int KT, int MODE>
__global__ __launch_bounds__(256) void k_gemm16(
    const _Float16* A1, int K1,
    const _Float16* __restrict__ A2, int K2,
    const unsigned short* __restrict__ Wp,
    const float* __restrict__ b1, const float* __restrict__ b2,
    float* __restrict__ O1, float* __restrict__ O2, float* __restrict__ O3,
    _Float16* Of16,
    const float* __restrict__ noise, const float* __restrict__ dis, int M) {
  __shared__ unsigned short wl[(KT / 8) * 1024];
  const int tid = threadIdx.x;
  const int l = tid & 63, wid = tid >> 6;
  const int row0 = blockIdx.x * 128;
  constexpr int totalU16 = (KT / 8) * 1024;
  for (int o = tid * 8; o < totalU16; o += 256 * 8) {
    *(uint4*)&wl[o] = *(const uint4*)&Wp[o];
  }
  __syncthreads();

  const int ar = l & 15, kg = l >> 4;
  f32x4 acc[2][8] = {};
  for (int k0 = 0; k0 < KT; k0 += 32) {
    const _Float16* Ab;
    int kl, Kb;
    if (k0 < K1) { Ab = A1; kl = k0; Kb = K1; }
    else         { Ab = A2; kl = k0 - K1; Kb = K2; }
    f16x8 a[2];
#pragma unroll
    for (int mt = 0; mt < 2; mt++) {
      int row = row0 + wid * 32 + mt * 16 + ar;
      if (row < M) {
        a[mt] = *(const f16x8*)&Ab[(size_t)row * Kb + kl + kg * 8];
      } else {
#pragma unroll
        for (int j = 0; j < 8; j++) a[mt][j] = (_Float16)0;
      }
    }
    int lb = ((k0 >> 3) + kg) * 1024 + ar * 8;
#pragma unroll
    for (int nt = 0; nt < 8; nt++) {
      f16x8 b = *(const f16x8*)&wl[lb + nt * 128];
#pragma unroll
      for (int mt = 0; mt < 2; mt++)
        acc[mt][nt] = __builtin_amdgcn_mfma_f32_16x16x32_f16(a[mt], b, acc[mt][nt], 0, 0, 0);
    }
  }

#pragma unroll
  for (int mt = 0; mt < 2; mt++) {
    int rbase = row0 + wid * 32 + mt * 16 + (l >> 4) * 4;
#pragma unroll
    for (int r = 0; r < 4; r++) {
      int rw = rbase + r;
      if (rw >= M) continue;
      if (MODE == 1) {
        float dr = dis[rw];
#pragma unroll
        for (int nt = 0; nt < 4; nt++) {
          int c = nt * 16 + (l & 15);
          float mv = acc[mt][nt][r] + b1[c];
          float lv = acc[mt][nt + 4][r] + b2[c];
          O1[(size_t)rw * 64 + c] = mv;
          O2[(size_t)rw * 64 + c] = lv;
          float z = noise[(size_t)rw * 64 + c] * expf(0.5f * lv) + mv;
          O3[(size_t)rw * 64 + c] = z;
          Of16[(size_t)rw * 64 + c] = (_Float16)(dr * z);
        }
      } else if (MODE == 0) {
        float dr = dis[rw];
#pragma unroll
        for (int nt = 0; nt < 8; nt++) {
          int c = nt * 16 + (l & 15);
          float v = tanhf(acc[mt][nt][r] + b1[c]);
          Of16[(size_t)rw * 128 + c] = (_Float16)(dr * v);
        }
      } else {
#pragma unroll
        for (int nt = 0; nt < 8; nt++) {
          int c = nt * 16 + (l & 15);
          O1[(size_t)rw * 128 + c] = acc[mt][nt][r] + b1[c];
        }
      }
    }
  }
}

// ---------------- P1 GEMM: fp32 [feat|cond] inputs, prescaled f16 out -----
__global__ __launch_bounds__(256) void k_gemmP1(
    const float* __restrict__ F, const float* __restrict__ Cnd,
    const unsigned short* __restrict__ Wp, _Float16* __restrict__ O,
    const float* __restrict__ dis, int M) {
  __shared__ unsigned short wl[20 * 1024];  // K=160
  const int tid = threadIdx.x;
  const int l = tid & 63, wid = tid >> 6;
  const int row0 = blockIdx.x * 128;
  for (int o = tid * 8; o < 20 * 1024; o += 256 * 8) {
    *(uint4*)&wl[o] = *(const uint4*)&Wp[o];
  }
  __syncthreads();

  const int ar = l & 15, kg = l >> 4;
  f32x4 acc[2][8] = {};
  for (int k0 = 0; k0 < 160; k0 += 32) {
    int col0 = k0 + kg * 8;
    f16x8 a[2];
#pragma unroll
    for (int mt = 0; mt < 2; mt++) {
      int row = row0 + wid * 32 + mt * 16 + ar;
      float4 u = {0, 0, 0, 0}, v = {0, 0, 0, 0};
      if (row < M) {
        if (col0 < 128) {
          u = *(const float4*)&F[(size_t)row * 128 + col0];
          v = *(const float4*)&F[(size_t)row * 128 + col0 + 4];
        } else {
          u = *(const float4*)&Cnd[(size_t)row * 32 + (col0 - 128)];
          v = *(const float4*)&Cnd[(size_t)row * 32 + (col0 - 124)];
        }
      }
      a[mt][0] = (_Float16)u.x; a[mt][1] = (_Float16)u.y;
      a[mt][2] = (_Float16)u.z; a[mt][3] = (_Float16)u.w;
      a[mt][4] = (_Float16)v.x; a[mt][5] = (_Float16)v.y;
      a[mt][6] = (_Float16)v.z; a[mt][7] = (_Float16)v.w;
    }
    int lb = ((k0 >> 3) + kg) * 1024 + ar * 8;
#pragma unroll
    for (int nt = 0; nt < 8; nt++) {
      f16x8 b = *(const f16x8*)&wl[lb + nt * 128];
#pragma unroll
      for (int mt = 0; mt < 2; mt++)
        acc[mt][nt] = __builtin_amdgcn_mfma_f32_16x16x32_f16(a[mt], b, acc[mt][nt], 0, 0, 0);
    }
  }
#pragma unroll
  for (int mt = 0; mt < 2; mt++) {
    int rbase = row0 + wid * 32 + mt * 16 + (l >> 4) * 4;
#pragma unroll
    for (int r = 0; r < 4; r++) {
      int rw = rbase + r;
      if (rw >= M) continue;
      float dr = dis[rw];
#pragma unroll
      for (int nt = 0; nt < 8; nt++) {
        int c = nt * 16 + (l & 15);
        O[(size_t)rw * 128 + c] = (_Float16)(dr * acc[mt][nt][r]);
      }
    }
  }
}

// ---------------------------------------------------------------------------

static inline size_t align_up(size_t x, size_t a) { return (x + a - 1) & ~(a - 1); }

extern "C" void kernel_launch(void* const* d_in, const int* in_sizes, int n_in,
                              void* d_out, int out_size, void* d_ws, size_t ws_size,
                              hipStream_t stream) {
  const float* feature   = (const float*)d_in[0];
  const float* condition = (const float*)d_in[1];
  const float* noise     = (const float*)d_in[2];
  const int*   ei        = (const int*)d_in[3];
  const float* Wenc1 = (const float*)d_in[4];  const float* benc1 = (const float*)d_in[5];
  const float* Wenc2 = (const float*)d_in[6];  const float* benc2 = (const float*)d_in[7];
  const float* Wm    = (const float*)d_in[8];  const float* bm    = (const float*)d_in[9];
  const float* Wlv   = (const float*)d_in[10]; const float* blv   = (const float*)d_in[11];
  const float* Wd1   = (const float*)d_in[12]; const float* bd1   = (const float*)d_in[13];
  const float* Wd2   = (const float*)d_in[14]; const float* bd2   = (const float*)d_in[15];
  const float* Wout  = (const float*)d_in[16]; const float* bout  = (const float*)d_in[17];

  const int N = in_sizes[0] / FEAT;
  const int E = in_sizes[3] / 2;

  // ---- d_out segments ----
  float* out = (float*)d_out;
  float* zseg    = out;
  float* meanseg = out + (size_t)N * LAT;
  float* lvseg   = out + (size_t)2 * N * LAT;
  float* outseg  = out + (size_t)3 * N * LAT;  // fp32 [N,128]; scratch until final GEMM

  char* ob = (char*)outseg;
  _Float16* zf16  = (_Float16*)ob;                          // [N,64]  prescaled z
  _Float16* condC = (_Float16*)(ob + (size_t)N * 64 * 2);   // [N,32]  prescaled cond
  uint* condCu = (uint*)condC;

  // ---- workspace ----
  char* w = (char*)d_ws;
  size_t off = 0;
  int*   degI   = (int*)(w + off);   off = align_up(off + (size_t)N * 4, 256);
  float* dis    = (float*)(w + off); off = align_up(off + (size_t)N * 4, 256);
  int*   ptr    = (int*)(w + off);   off = align_up(off + (size_t)N * 4, 256);
  int*   blkSum = (int*)(w + off);   off = align_up(off + 4096, 256);
  int*   blkOff = (int*)(w + off);   off = align_up(off + 4096, 256);
  int*   csr    = (int*)(w + off);   off = align_up(off + (size_t)(E + 64) * 4, 256);
  unsigned short* WpE1 = (unsigned short*)(w + off); off = align_up(off + 160 * 128 * 2, 256);
  unsigned short* WpE2 = (unsigned short*)(w + off); off = align_up(off + 128 * 128 * 2, 256);
  unsigned short* WpML = (unsigned short*)(w + off); off = align_up(off + 128 * 128 * 2, 256);
  unsigned short* WpD1 = (unsigned short*)(w + off); off = align_up(off + 96 * 128 * 2, 256);
  unsigned short* WpD2 = (unsigned short*)(w + off); off = align_up(off + 128 * 128 * 2, 256);
  unsigned short* WpO  = (unsigned short*)(w + off); off = align_up(off + 128 * 128 * 2, 256);
  _Float16* S  = (_Float16*)(w + off); off = align_up(off + (size_t)N * 32 * 2, 256);
  _Float16* TA = (_Float16*)(w + off); off = align_up(off + (size_t)N * 128 * 2, 256);
  _Float16* TB = (_Float16*)(w + off); off = align_up(off + (size_t)N * 128 * 2, 256);
  // partial-count slab aliases the first 12.8 MB of TA (dead before TA written)
  int* part = (int*)TA;  // [NG*BPG][RANGE]

  const int TB_ = 256;
  dim3 blk(TB_);
  dim3 gN((N + TB_ - 1) / TB_);
  const int nScanBlk = (N + 1023) / 1024;
  dim3 gAgg((N + 3) / 4);
  dim3 gG((N + 127) / 128);
  dim3 gPart(NG * BPG);

  // ---- graph prep (no global atomics) ----
  k_hist<<<gPart, blk, 0, stream>>>(ei + E, part, E, N);
  k_scan1<<<dim3(nScanBlk), blk, 0, stream>>>(part, degI, dis, ptr, blkSum, N);
  k_scan2<<<dim3(1), blk, 0, stream>>>(blkSum, blkOff, nScanBlk);
  k_scan3<<<gN, blk, 0, stream>>>(ptr, blkOff, N);
  k_cum<<<gN, blk, 0, stream>>>(part, ptr, N);
  k_fill2<<<gPart, blk, 0, stream>>>(ei, part, csr, E, N);

  // ---- cond cast + weight packing ----
  k_cast<5><<<dim3(((size_t)N * 32 / 4 + TB_ - 1) / TB_), blk, 0, stream>>>(
      condition, condCu, dis, N * 32 / 4);
  {
    PWArr pa;
    pa.d[0] = {Wenc1, WpE1, 160, 128, 0, 128};
    pa.d[1] = {Wenc2, WpE2, 128, 128, 0, 128};
    pa.d[2] = {Wm,    WpML, 128, 64,  0, 128};
    pa.d[3] = {Wlv,   WpML, 128, 64, 64, 128};
    pa.d[4] = {Wd1,   WpD1,  96, 128, 0, 128};
    pa.d[5] = {Wd2,   WpD2, 128, 128, 0, 128};
    pa.d[6] = {Wout,  WpO,  128, 128, 0, 128};
    k_packw<<<dim3(80, 7), blk, 0, stream>>>(pa);
  }

  // ---- encoder ----
  k_gemmP1<<<gG, blk, 0, stream>>>(feature, condition, WpE1, TA, dis, N);
  k_aggh<HID, 1><<<gAgg, blk, 0, stream>>>(TA, TB, degI, dis, ptr, csr, benc1, N);
  k_aggh<HID, 0><<<gAgg, blk, 0, stream>>>(TB, TA, degI, dis, ptr, csr, nullptr, N);
  k_gemm16<128, 0><<<gG, blk, 0, stream>>>(
      TA, HID, nullptr, 0, WpE2, benc2, nullptr,
      nullptr, nullptr, nullptr, TA, nullptr, dis, N);
  k_aggh<HID, 0><<<gAgg, blk, 0, stream>>>(TA, TB, degI, dis, ptr, csr, nullptr, N);
  k_gemm16<128, 1><<<gG, blk, 0, stream>>>(
      TB, HID, nullptr, 0, WpML, bm, blv,
      meanseg, lvseg, zseg, zf16, noise, dis, N);

  // ---- decoder ----
  k_aggh<COND, 0><<<gAgg, blk, 0, stream>>>(condC, S, degI, dis, ptr, csr, nullptr, N);
  k_aggh<LAT, 0><<<gAgg, blk, 0, stream>>>(zf16, TA, degI, dis, ptr, csr, nullptr, N);
  k_gemm16<96, 0><<<gG, blk, 0, stream>>>(
      TA, LAT, S, COND, WpD1, bd1, nullptr,
      nullptr, nullptr, nullptr, TB, nullptr, dis, N);
  k_aggh<HID, 0><<<gAgg, blk, 0, stream>>>(TB, TA, degI, dis, ptr, csr, nullptr, N);
  k_gemm16<128, 0><<<gG, blk, 0, stream>>>(
      TA, HID, nullptr, 0, WpD2, bd2, nullptr,
      nullptr, nullptr, nullptr, TA, nullptr, dis, N);
  k_aggh<HID, 0><<<gAgg, blk, 0, stream>>>(TA, TB, degI, dis, ptr, csr, nullptr, N);
  k_gemm16<128, 2><<<gG, blk, 0, stream>>>(
      TB, HID, nullptr, 0, WpO, bout, nullptr,
      outseg, nullptr, nullptr, nullptr, nullptr, dis, N);
}